// Round 4
// baseline (2937.538 us; speedup 1.0000x reference)
//
#include <hip/hip_runtime.h>
#include <hip/hip_bf16.h>

#define NN 50000
#define RR 500
#define DD 300
#define HH 600
#define EE 500000

typedef short bf16x8 __attribute__((ext_vector_type(8)));
typedef float f32x4  __attribute__((ext_vector_type(4)));

__device__ __forceinline__ short f2bf(float f){
  union { float f; unsigned u; } v; v.f = f;
  unsigned r = v.u + 0x7fffu + ((v.u >> 16) & 1u);   // RNE
  return (short)(r >> 16);
}

// ---------------- colsum of head_r / tail_r ----------------
__global__ void k_colsum(const float* __restrict__ head, const float* __restrict__ tail,
                         float* __restrict__ hs, float* __restrict__ ts){
  const float* src = blockIdx.y ? tail : head;
  float* dst = blockIdx.y ? ts : hs;
  int t = threadIdx.x;
  int r0 = blockIdx.x * 256;
  int r1 = r0 + 256; if (r1 > NN) r1 = NN;
  if (t < RR){
    float a = 0.f;
    for (int r = r0; r < r1; ++r) a += src[r * RR + t];
    atomicAdd(&dst[t], a);
  }
}

// ---------------- histograms ----------------
__global__ void k_hist_lds(const int* __restrict__ v, int n, int nb, int* __restrict__ bins){
  extern __shared__ int lb[];
  for (int i = threadIdx.x; i < nb; i += blockDim.x) lb[i] = 0;
  __syncthreads();
  for (int i = blockIdx.x * blockDim.x + threadIdx.x; i < n; i += gridDim.x * blockDim.x)
    atomicAdd(&lb[v[i]], 1);
  __syncthreads();
  for (int i = threadIdx.x; i < nb; i += blockDim.x) if (lb[i]) atomicAdd(&bins[i], lb[i]);
}

__global__ void k_hist_glob(const int* __restrict__ v, int n, int* __restrict__ bins){
  for (int i = blockIdx.x * blockDim.x + threadIdx.x; i < n; i += gridDim.x * blockDim.x)
    atomicAdd(&bins[v[i]], 1);
}

// ---------------- scan (exclusive) ----------------
__global__ void k_scan_part(const int* __restrict__ cnt, int n, int* __restrict__ incl, int* __restrict__ bsum){
  __shared__ int s[256];
  int i = blockIdx.x * 256 + threadIdx.x;
  int v = (i < n) ? cnt[i] : 0;
  s[threadIdx.x] = v; __syncthreads();
  for (int off = 1; off < 256; off <<= 1){
    int t = (threadIdx.x >= off) ? s[threadIdx.x - off] : 0;
    __syncthreads();
    s[threadIdx.x] += t;
    __syncthreads();
  }
  if (i < n) incl[i] = s[threadIdx.x];
  if (threadIdx.x == 255) bsum[blockIdx.x] = s[255];
}

__global__ void k_scan_mid(const int* __restrict__ bsum, int nb, int* __restrict__ boff){
  if (threadIdx.x == 0 && blockIdx.x == 0){
    int run = 0;
    for (int b = 0; b < nb; ++b){ boff[b] = run; run += bsum[b]; }
  }
}

__global__ void k_scan_add(const int* __restrict__ incl, const int* __restrict__ cnt,
                           const int* __restrict__ boff, int n,
                           int* __restrict__ rowst, int* __restrict__ cur){
  int i = blockIdx.x * 256 + threadIdx.x;
  if (i < n){
    int v = incl[i] - cnt[i] + boff[blockIdx.x];
    rowst[i] = v; cur[i] = v;
  }
}

// ---------------- CSR scatter ----------------
__global__ void k_scatter_r(const int* __restrict__ dst, const int* __restrict__ src,
                            const int* __restrict__ rv, int n, int* __restrict__ cur,
                            int* __restrict__ colv, int* __restrict__ rvv){
  for (int i = blockIdx.x * blockDim.x + threadIdx.x; i < n; i += gridDim.x * blockDim.x){
    int p = atomicAdd(&cur[dst[i]], 1);
    colv[p] = src[i]; rvv[p] = rv[i];
  }
}

__global__ void k_scatter_m(const int* __restrict__ dst, const int* __restrict__ src,
                            const float* __restrict__ mv, int n, int* __restrict__ cur,
                            int* __restrict__ colv, float* __restrict__ mvv){
  for (int i = blockIdx.x * blockDim.x + threadIdx.x; i < n; i += gridDim.x * blockDim.x){
    int p = atomicAdd(&cur[dst[i]], 1);
    colv[p] = src[i]; mvv[p] = mv[i];
  }
}

// ---------------- compute_r GEMM: acc[m,d] = sum_k A[m,k]*X[k,d]
// A[m,k] = head[k,m] (m<500) or tail[k,m-500]; M=1000, Ncols=300, K=50000, K-split 32
__global__ __launch_bounds__(256) void k_gemm_cr(
    const float* __restrict__ head, const float* __restrict__ tail,
    const float* __restrict__ X, float* __restrict__ acc)
{
  const int m0 = blockIdx.x * 128;
  const int n0 = blockIdx.y * 128;
  const int k0 = blockIdx.z * 1568;
  int kend = k0 + 1568; if (kend > NN) kend = NN;

  __shared__ short As[128][40];
  __shared__ short Bs[128][40];
  const int tid = threadIdx.x;
  const int lane = tid & 63, wave = tid >> 6;
  const int wr = wave >> 1, wc = wave & 1;

  f32x4 c[4][4];
  #pragma unroll
  for (int i = 0; i < 4; ++i)
    #pragma unroll
    for (int j = 0; j < 4; ++j)
      #pragma unroll
      for (int q = 0; q < 4; ++q) c[i][j][q] = 0.f;

  for (int kk = k0; kk < kend; kk += 32){
    // A: 128 m x 32 k; global contiguous in m (head row layout [N][R])
    #pragma unroll
    for (int u = 0; u < 4; ++u){
      int f4 = tid + u * 256;
      int kl = f4 >> 5;
      int ml = (f4 & 31) * 4;
      int kg = kk + kl;
      int mg = m0 + ml;
      float4 v = {0.f, 0.f, 0.f, 0.f};
      if (kg < kend && mg < 1000){
        v = (mg < RR) ? *(const float4*)(head + kg * RR + mg)
                      : *(const float4*)(tail + kg * RR + (mg - RR));
      }
      As[ml + 0][kl] = f2bf(v.x);
      As[ml + 1][kl] = f2bf(v.y);
      As[ml + 2][kl] = f2bf(v.z);
      As[ml + 3][kl] = f2bf(v.w);
    }
    // B: 32 k x 128 n from X[k][n]
    #pragma unroll
    for (int u = 0; u < 4; ++u){
      int f4 = tid + u * 256;
      int kl = f4 >> 5;
      int nl = (f4 & 31) * 4;
      int kg = kk + kl;
      int ng = n0 + nl;
      float4 v = {0.f, 0.f, 0.f, 0.f};
      if (kg < kend && ng < DD) v = *(const float4*)(X + kg * DD + ng);
      Bs[nl + 0][kl] = f2bf(v.x);
      Bs[nl + 1][kl] = f2bf(v.y);
      Bs[nl + 2][kl] = f2bf(v.z);
      Bs[nl + 3][kl] = f2bf(v.w);
    }
    __syncthreads();
    const int krow = (lane >> 4) * 8;
    const int rsel = lane & 15;
    bf16x8 af[4], bfr[4];
    #pragma unroll
    for (int i = 0; i < 4; ++i){
      af[i]  = *(const bf16x8*)(&As[wr * 64 + i * 16 + rsel][krow]);
      bfr[i] = *(const bf16x8*)(&Bs[wc * 64 + i * 16 + rsel][krow]);
    }
    #pragma unroll
    for (int i = 0; i < 4; ++i)
      #pragma unroll
      for (int j = 0; j < 4; ++j)
        c[i][j] = __builtin_amdgcn_mfma_f32_16x16x32_bf16(af[i], bfr[j], c[i][j], 0, 0, 0);
    __syncthreads();
  }
  const int col = lane & 15;
  const int rw0 = (lane >> 4) * 4;
  #pragma unroll
  for (int j = 0; j < 4; ++j){
    int dg = n0 + wc * 64 + j * 16 + col;
    if (dg >= DD) continue;
    #pragma unroll
    for (int i = 0; i < 4; ++i){
      int mg = m0 + wr * 64 + i * 16 + rw0;
      #pragma unroll
      for (int q = 0; q < 4; ++q)
        if (mg + q < 1000) atomicAdd(acc + (mg + q) * DD + dg, c[i][j][q]);
    }
  }
}

// ---------------- assemble dual_X from acc ----------------
__global__ void k_assemble(const float* __restrict__ acc, const float* __restrict__ hs,
                           const float* __restrict__ ts, float* __restrict__ dualX){
  int i = blockIdx.x * 256 + threadIdx.x;
  if (i < RR * DD){
    int r = i / DD, d = i - r * DD;
    dualX[r * HH + d]      = acc[r * DD + d]          / (hs[r] + 1e-9f);
    dualX[r * HH + DD + d] = acc[(RR + r) * DD + d]   / (ts[r] + 1e-9f);
  }
}

// ---------------- h = feat @ W.T + bias  (f32, [500,600]x[600,600]^T) ----------------
__global__ __launch_bounds__(256) void k_hgemm(const float* __restrict__ feat, const float* __restrict__ W,
                                               const float* __restrict__ bias, float* __restrict__ h){
  __shared__ float Fs[16][17], Ws[16][17];
  int tx = threadIdx.x & 15, ty = threadIdx.x >> 4;
  int r0 = blockIdx.x * 16, j0 = blockIdx.y * 16;
  float acc = 0.f;
  for (int k0 = 0; k0 < HH; k0 += 16){
    int k = k0 + tx;
    Fs[ty][tx] = (r0 + ty < RR && k < HH) ? feat[(r0 + ty) * HH + k] : 0.f;
    Ws[ty][tx] = (j0 + ty < HH && k < HH) ? W[(j0 + ty) * HH + k] : 0.f;
    __syncthreads();
    #pragma unroll
    for (int kk = 0; kk < 16; ++kk) acc += Fs[ty][kk] * Ws[tx][kk];
    __syncthreads();
  }
  int rr = r0 + ty, jj = j0 + tx;
  if (rr < RR && jj < HH) h[rr * HH + jj] = acc + (bias ? bias[jj] : 0.f);
}

// ---------------- per-row dots: f1[r]=h[r]·a1+b1, f2[r]=h[r]·a2+b2 ----------------
__global__ void k_rowdot2(const float* __restrict__ Hm, const float* __restrict__ a1, const float* __restrict__ b1,
                          const float* __restrict__ a2, const float* __restrict__ b2,
                          float* __restrict__ f1, float* __restrict__ f2){
  int wave = threadIdx.x >> 6, lane = threadIdx.x & 63;
  int r = blockIdx.x * 4 + wave;
  if (r >= RR) return;
  float s1 = 0.f, s2 = 0.f;
  for (int k = lane; k < HH; k += 64){
    float hv = Hm[r * HH + k];
    s1 += hv * a1[k];
    if (a2) s2 += hv * a2[k];
  }
  #pragma unroll
  for (int off = 32; off; off >>= 1){
    s1 += __shfl_down(s1, off);
    s2 += __shfl_down(s2, off);
  }
  if (lane == 0){
    f1[r] = s1 + b1[0];
    if (f2) f2[r] = s2 + (b2 ? b2[0] : 0.f);
  }
}

// ---------------- fused dense attention row: softmax + coefs@val + relu ----------------
__global__ __launch_bounds__(512) void k_attrow(const float* __restrict__ f1, const float* __restrict__ f2,
    const float* __restrict__ adj, const float* __restrict__ val, float* __restrict__ outp){
  __shared__ float coef[RR];
  __shared__ float red[512];
  int r = blockIdx.x, t = threadIdx.x;
  float lg = -3.0e38f;
  if (t < RR){
    float l = f1[r] + f2[t];
    l = (l > 0.f) ? l : 0.01f * l;
    if (adj[r * RR + t] <= 0.f) l -= 1e9f;
    lg = l;
  }
  red[t] = lg; __syncthreads();
  for (int off = 256; off; off >>= 1){ if (t < off) red[t] = fmaxf(red[t], red[t + off]); __syncthreads(); }
  float mx = red[0]; __syncthreads();
  float e = (t < RR) ? expf(lg - mx) : 0.f;
  red[t] = e; __syncthreads();
  for (int off = 256; off; off >>= 1){ if (t < off) red[t] += red[t + off]; __syncthreads(); }
  float inv = 1.f / red[0]; __syncthreads();
  if (t < RR) coef[t] = e * inv;
  __syncthreads();
  float acc1 = 0.f, acc2 = 0.f;
  int d2 = t + 512;
  for (int j = 0; j < RR; ++j){
    float cj = coef[j];
    acc1 += cj * val[j * HH + t];
    if (d2 < HH) acc2 += cj * val[j * HH + d2];
  }
  outp[r * HH + t] = fmaxf(acc1, 0.f);
  if (d2 < HH) outp[r * HH + d2] = fmaxf(acc2, 0.f);
}

// ---------------- global-softmax coefficients per relation ----------------
__global__ void k_cvec(const float* __restrict__ tv, const int* __restrict__ cnt, float* __restrict__ cvec){
  __shared__ float red[512];
  int t = threadIdx.x;
  float lr = -3.0e38f, tval = 0.f;
  if (t < RR){
    tval = tv[t];
    tval = (tval > 0.f) ? tval : 0.01f * tval;
    if (cnt[t] > 0) lr = tval;
  }
  red[t] = lr; __syncthreads();
  for (int off = 256; off; off >>= 1){ if (t < off) red[t] = fmaxf(red[t], red[t + off]); __syncthreads(); }
  float mx = red[0]; __syncthreads();
  float ex = (t < RR) ? expf(tval - mx) : 0.f;
  red[t] = (t < RR) ? ex * (float)cnt[t] : 0.f; __syncthreads();
  for (int off = 256; off; off >>= 1){ if (t < off) red[t] += red[t + off]; __syncthreads(); }
  float inv = 1.f / red[0];
  if (t < RR) cvec[t] = ex * inv;
}

// ---------------- sparse att SpMM: out = base + scale*relu(sum c[rv]*X[src]) ----------------
__global__ __launch_bounds__(256) void k_spmm_r(const int* __restrict__ rowst, const int* __restrict__ rowcnt,
    const int* __restrict__ colv, const int* __restrict__ rvv, const float* __restrict__ cvec,
    const float* __restrict__ Xg, const float* __restrict__ base, float scale, float* __restrict__ outp){
  int wave = threadIdx.x >> 6, lane = threadIdx.x & 63;
  int row = blockIdx.x * 4 + wave;
  if (row >= NN) return;
  int st = rowst[row], cn = rowcnt[row];
  float a0 = 0.f, a1 = 0.f, a2 = 0.f, a3 = 0.f, a4 = 0.f;
  for (int e = 0; e < cn; ++e){
    int s = colv[st + e];
    float w = cvec[rvv[st + e]];
    const float* xr = Xg + (size_t)s * DD;
    a0 += w * xr[lane];
    a1 += w * xr[lane + 64];
    a2 += w * xr[lane + 128];
    a3 += w * xr[lane + 192];
    if (lane < 44) a4 += w * xr[lane + 256];
  }
  size_t ro = (size_t)row * DD;
  outp[ro + lane]       = base[ro + lane]       + scale * fmaxf(a0, 0.f);
  outp[ro + lane + 64]  = base[ro + lane + 64]  + scale * fmaxf(a1, 0.f);
  outp[ro + lane + 128] = base[ro + lane + 128] + scale * fmaxf(a2, 0.f);
  outp[ro + lane + 192] = base[ro + lane + 192] + scale * fmaxf(a3, 0.f);
  if (lane < 44) outp[ro + lane + 256] = base[ro + lane + 256] + scale * fmaxf(a4, 0.f);
}

// ---------------- diag-GCN SpMM + highway blend ----------------
__global__ __launch_bounds__(256) void k_spmm_m(const int* __restrict__ rowst, const int* __restrict__ rowcnt,
    const int* __restrict__ colv, const float* __restrict__ mvv,
    const float* __restrict__ Xg, const float* __restrict__ w0, const float* __restrict__ tg,
    const float* __restrict__ base, float* __restrict__ outp){
  int wave = threadIdx.x >> 6, lane = threadIdx.x & 63;
  int row = blockIdx.x * 4 + wave;
  if (row >= NN) return;
  int st = rowst[row], cn = rowcnt[row];
  float a0 = 0.f, a1 = 0.f, a2 = 0.f, a3 = 0.f, a4 = 0.f;
  for (int e = 0; e < cn; ++e){
    int s = colv[st + e];
    float w = mvv[st + e];
    const float* xr = Xg + (size_t)s * DD;
    a0 += w * xr[lane];
    a1 += w * xr[lane + 64];
    a2 += w * xr[lane + 128];
    a3 += w * xr[lane + 192];
    if (lane < 44) a4 += w * xr[lane + 256];
  }
  size_t ro = (size_t)row * DD;
  #pragma unroll
  for (int u = 0; u < 5; ++u){
    int d = lane + u * 64;
    if (d < DD){
      float acc = (u == 0) ? a0 : (u == 1) ? a1 : (u == 2) ? a2 : (u == 3) ? a3 : a4;
      float g = fmaxf(w0[d] * acc, 0.f);
      float tvv = tg[ro + d];
      outp[ro + d] = tvv * g + (1.f - tvv) * base[ro + d];
    }
  }
}

// ---------------- highway gate GEMM: Tg = sigmoid(Xin @ Wg + bg), M=50000,K=N=300 ----------------
__global__ __launch_bounds__(256) void k_gate(const float* __restrict__ Xin, const float* __restrict__ Wg,
                                              const float* __restrict__ bg, float* __restrict__ Tg){
  const int m0 = blockIdx.x * 128, n0 = blockIdx.y * 128;
  __shared__ short As[128][40];
  __shared__ short Bs[128][40];
  const int tid = threadIdx.x;
  const int lane = tid & 63, wave = tid >> 6;
  const int wr = wave >> 1, wc = wave & 1;
  f32x4 c[4][4];
  #pragma unroll
  for (int i = 0; i < 4; ++i)
    #pragma unroll
    for (int j = 0; j < 4; ++j)
      #pragma unroll
      for (int q = 0; q < 4; ++q) c[i][j][q] = 0.f;

  for (int kk = 0; kk < DD; kk += 32){
    // A: k-contiguous
    #pragma unroll
    for (int u = 0; u < 4; ++u){
      int f4 = tid + u * 256;
      int ml = f4 >> 3;
      int kl = (f4 & 7) * 4;
      int mg = m0 + ml, kg = kk + kl;
      float4 v = {0.f, 0.f, 0.f, 0.f};
      if (mg < NN && kg < DD) v = *(const float4*)(Xin + (size_t)mg * DD + kg);
      ushort4 w = make_ushort4((unsigned short)f2bf(v.x), (unsigned short)f2bf(v.y),
                               (unsigned short)f2bf(v.z), (unsigned short)f2bf(v.w));
      *reinterpret_cast<ushort4*>(&As[ml][kl]) = w;
    }
    // B: transpose-stage Wg[k][n] -> Bs[n][k]
    #pragma unroll
    for (int u = 0; u < 4; ++u){
      int f4 = tid + u * 256;
      int kl = f4 >> 5;
      int nl = (f4 & 31) * 4;
      int kg = kk + kl, ng = n0 + nl;
      float4 v = {0.f, 0.f, 0.f, 0.f};
      if (kg < DD && ng < DD) v = *(const float4*)(Wg + kg * DD + ng);
      Bs[nl + 0][kl] = f2bf(v.x);
      Bs[nl + 1][kl] = f2bf(v.y);
      Bs[nl + 2][kl] = f2bf(v.z);
      Bs[nl + 3][kl] = f2bf(v.w);
    }
    __syncthreads();
    const int krow = (lane >> 4) * 8;
    const int rsel = lane & 15;
    bf16x8 af[4], bfr[4];
    #pragma unroll
    for (int i = 0; i < 4; ++i){
      af[i]  = *(const bf16x8*)(&As[wr * 64 + i * 16 + rsel][krow]);
      bfr[i] = *(const bf16x8*)(&Bs[wc * 64 + i * 16 + rsel][krow]);
    }
    #pragma unroll
    for (int i = 0; i < 4; ++i)
      #pragma unroll
      for (int j = 0; j < 4; ++j)
        c[i][j] = __builtin_amdgcn_mfma_f32_16x16x32_bf16(af[i], bfr[j], c[i][j], 0, 0, 0);
    __syncthreads();
  }
  const int col = lane & 15;
  const int rw0 = (lane >> 4) * 4;
  #pragma unroll
  for (int j = 0; j < 4; ++j){
    int ng = n0 + wc * 64 + j * 16 + col;
    if (ng >= DD) continue;
    float bias = bg[ng];
    #pragma unroll
    for (int i = 0; i < 4; ++i){
      int mg = m0 + wr * 64 + i * 16 + rw0;
      #pragma unroll
      for (int q = 0; q < 4; ++q){
        if (mg + q < NN){
          float x = c[i][j][q] + bias;
          Tg[(size_t)(mg + q) * DD + ng] = 1.f / (1.f + expf(-x));
        }
      }
    }
  }
}

// ================= host =================
extern "C" void kernel_launch(void* const* d_in, const int* in_sizes, int n_in,
                              void* d_out, int out_size, void* d_ws, size_t ws_size,
                              hipStream_t stream)
{
  (void)in_sizes; (void)n_in; (void)out_size; (void)ws_size;
  const float* X0   = (const float*)d_in[0];
  const float* head = (const float*)d_in[1];
  const float* tail = (const float*)d_in[2];
  const float* adj  = (const float*)d_in[3];
  const int*   ridx = (const int*)d_in[4];
  const int*   rval = (const int*)d_in[5];
  const int*   midx = (const int*)d_in[6];
  const float* mval = (const float*)d_in[7];
  const float* W_s  = (const float*)d_in[8];
  const float* a1_s = (const float*)d_in[9];
  const float* b1_s = (const float*)d_in[10];
  const float* a2_s = (const float*)d_in[11];
  const float* b2_s = (const float*)d_in[12];
  const float* w_sp1= (const float*)d_in[13];
  const float* b_sp1= (const float*)d_in[14];
  const float* w_sp2= (const float*)d_in[15];
  const float* b_sp2= (const float*)d_in[16];
  const float* W_d  = (const float*)d_in[17];
  const float* b_d  = (const float*)d_in[18];
  const float* a1_d = (const float*)d_in[19];
  const float* b1_d = (const float*)d_in[20];
  const float* a2_d = (const float*)d_in[21];
  const float* b2_d = (const float*)d_in[22];
  const float* w0_1 = (const float*)d_in[23];
  const float* w0_2 = (const float*)d_in[24];
  const float* Wg1  = (const float*)d_in[25];
  const float* bg1  = (const float*)d_in[26];
  const float* Wg2  = (const float*)d_in[27];
  const float* bg2  = (const float*)d_in[28];

  char* ws = (char*)d_ws;
  size_t off = 0;
  auto alloc = [&](size_t bytes)->char*{
    char* p = ws + off;
    off += (bytes + 255) & ~(size_t)255;
    return p;
  };
  float* acc    = (float*)alloc(1000 * DD * 4);
  float* X1GC   = (float*)alloc((size_t)NN * DD * 4);
  float* X2     = (float*)alloc((size_t)NN * DD * 4);
  float* TG     = (float*)alloc((size_t)NN * DD * 4);
  float* dualX  = (float*)alloc(RR * HH * 4);
  float* dualH1 = (float*)alloc(RR * HH * 4);
  float* dualH2 = (float*)alloc(RR * HH * 4);
  float* hbuf   = (float*)alloc(RR * HH * 4);
  float* hs     = (float*)alloc(2048);
  float* ts     = (float*)alloc(2048);
  int*   cntR   = (int*)alloc(2048);
  float* f1     = (float*)alloc(2048);
  float* f2     = (float*)alloc(2048);
  float* tv     = (float*)alloc(2048);
  float* cv     = (float*)alloc(2048);
  int* rowcntR  = (int*)alloc((size_t)NN * 4);
  int* rowstR   = (int*)alloc((size_t)NN * 4);
  int* curR     = (int*)alloc((size_t)NN * 4);
  int* colR     = (int*)alloc((size_t)EE * 4);
  int* rvR      = (int*)alloc((size_t)EE * 4);
  int* rowcntM  = (int*)alloc((size_t)NN * 4);
  int* rowstM   = (int*)alloc((size_t)NN * 4);
  int* curM     = (int*)alloc((size_t)NN * 4);
  int* colM     = (int*)alloc((size_t)EE * 4);
  float* mvM    = (float*)alloc((size_t)EE * 4);
  int* incl     = (int*)alloc((size_t)NN * 4);
  int* bsum     = (int*)alloc(1024);
  int* boff     = (int*)alloc(1024);

  float* OUT0 = (float*)d_out;
  float* OUT1 = (float*)d_out + (size_t)NN * DD;

  // zero init (hs, ts, cntR are contiguous 256-aligned allocs)
  hipMemsetAsync(hs, 0, 3 * 2048, stream);
  hipMemsetAsync(rowcntR, 0, (size_t)NN * 4, stream);
  hipMemsetAsync(rowcntM, 0, (size_t)NN * 4, stream);

  // ---- static prep ----
  k_colsum<<<dim3(196, 2), 512, 0, stream>>>(head, tail, hs, ts);
  k_hist_lds<<<256, 256, RR * 4, stream>>>(rval, EE, RR, cntR);
  k_hist_glob<<<512, 256, 0, stream>>>(ridx, EE, rowcntR);
  k_scan_part<<<196, 256, 0, stream>>>(rowcntR, NN, incl, bsum);
  k_scan_mid<<<1, 1, 0, stream>>>(bsum, 196, boff);
  k_scan_add<<<196, 256, 0, stream>>>(incl, rowcntR, boff, NN, rowstR, curR);
  k_scatter_r<<<512, 256, 0, stream>>>(ridx, ridx + EE, rval, EE, curR, colR, rvR);
  k_hist_glob<<<512, 256, 0, stream>>>(midx, EE, rowcntM);
  k_scan_part<<<196, 256, 0, stream>>>(rowcntM, NN, incl, bsum);
  k_scan_mid<<<1, 1, 0, stream>>>(bsum, 196, boff);
  k_scan_add<<<196, 256, 0, stream>>>(incl, rowcntM, boff, NN, rowstM, curM);
  k_scatter_m<<<512, 256, 0, stream>>>(midx, midx + EE, mval, EE, curM, colM, mvM);

  // ---- round 1 ----
  hipMemsetAsync(acc, 0, 1000 * DD * 4, stream);
  k_gemm_cr<<<dim3(8, 3, 32), 256, 0, stream>>>(head, tail, X0, acc);
  k_assemble<<<586, 256, 0, stream>>>(acc, hs, ts, dualX);
  k_hgemm<<<dim3(32, 38), 256, 0, stream>>>(dualX, W_s, nullptr, hbuf);
  k_rowdot2<<<125, 256, 0, stream>>>(hbuf, a1_s, b1_s, a2_s, b2_s, f1, f2);
  k_attrow<<<500, 512, 0, stream>>>(f1, f2, adj, dualX, dualH1);
  k_rowdot2<<<125, 256, 0, stream>>>(dualH1, w_sp1, b_sp1, nullptr, nullptr, tv, nullptr);
  k_cvec<<<1, 512, 0, stream>>>(tv, cntR, cv);
  k_spmm_r<<<12500, 256, 0, stream>>>(rowstR, rowcntR, colR, rvR, cv, X0, X0, 0.1f, X1GC);

  // ---- round 2 ----
  hipMemsetAsync(acc, 0, 1000 * DD * 4, stream);
  k_gemm_cr<<<dim3(8, 3, 32), 256, 0, stream>>>(head, tail, X1GC, acc);
  k_assemble<<<586, 256, 0, stream>>>(acc, hs, ts, dualX);
  k_hgemm<<<dim3(32, 38), 256, 0, stream>>>(dualX, W_d, b_d, hbuf);
  k_rowdot2<<<125, 256, 0, stream>>>(hbuf, a1_d, b1_d, a2_d, b2_d, f1, f2);
  k_attrow<<<500, 512, 0, stream>>>(f1, f2, adj, dualH1, dualH2);
  k_rowdot2<<<125, 256, 0, stream>>>(dualH2, w_sp2, b_sp2, nullptr, nullptr, tv, nullptr);
  k_cvec<<<1, 512, 0, stream>>>(tv, cntR, cv);
  k_spmm_r<<<12500, 256, 0, stream>>>(rowstR, rowcntR, colR, rvR, cv, X1GC, X0, 0.3f, X2);

  // ---- GCN + highway ----
  k_gate<<<dim3(391, 3), 256, 0, stream>>>(X2, Wg1, bg1, TG);
  k_spmm_m<<<12500, 256, 0, stream>>>(rowstM, rowcntM, colM, mvM, X2, w0_1, TG, X2, X1GC);
  k_gate<<<dim3(391, 3), 256, 0, stream>>>(X1GC, Wg2, bg2, TG);
  k_spmm_m<<<12500, 256, 0, stream>>>(rowstM, rowcntM, colM, mvM, X1GC, w0_2, TG, X1GC, OUT0);

  // ---- round 3 (dual only) ----
  hipMemsetAsync(acc, 0, 1000 * DD * 4, stream);
  k_gemm_cr<<<dim3(8, 3, 32), 256, 0, stream>>>(head, tail, OUT0, acc);
  k_assemble<<<586, 256, 0, stream>>>(acc, hs, ts, dualX);
  k_hgemm<<<dim3(32, 38), 256, 0, stream>>>(dualX, W_d, b_d, hbuf);
  k_rowdot2<<<125, 256, 0, stream>>>(hbuf, a1_d, b1_d, a2_d, b2_d, f1, f2);
  k_attrow<<<500, 512, 0, stream>>>(f1, f2, adj, dualH2, OUT1);
}

// Round 5
// 2327.848 us; speedup vs baseline: 1.2619x; 1.2619x over previous
//
#include <hip/hip_runtime.h>
#include <hip/hip_bf16.h>

#define NN 50000
#define RR 500
#define DD 300
#define HH 600
#define EE 500000
#define KP 50176      // 50000 padded to multiple of 32 (32 k-splits x 1568)
#define KPW 320       // 300 padded to multiple of 32 (gate GEMM K)

typedef short bf16x8 __attribute__((ext_vector_type(8)));
typedef float f32x4  __attribute__((ext_vector_type(4)));

__device__ __forceinline__ short f2bf(float f){
  union { float f; unsigned u; } v; v.f = f;
  unsigned r = v.u + 0x7fffu + ((v.u >> 16) & 1u);   // RNE
  return (short)(r >> 16);
}

// ---------------- colsum of head_r / tail_r ----------------
__global__ void k_colsum(const float* __restrict__ head, const float* __restrict__ tail,
                         float* __restrict__ hs, float* __restrict__ ts){
  const float* src = blockIdx.y ? tail : head;
  float* dst = blockIdx.y ? ts : hs;
  int t = threadIdx.x;
  int r0 = blockIdx.x * 256;
  int r1 = r0 + 256; if (r1 > NN) r1 = NN;
  if (t < RR){
    float a = 0.f;
    for (int r = r0; r < r1; ++r) a += src[r * RR + t];
    atomicAdd(&dst[t], a);
  }
}

// ---------------- histograms ----------------
__global__ void k_hist_lds(const int* __restrict__ v, int n, int nb, int* __restrict__ bins){
  extern __shared__ int lb[];
  for (int i = threadIdx.x; i < nb; i += blockDim.x) lb[i] = 0;
  __syncthreads();
  for (int i = blockIdx.x * blockDim.x + threadIdx.x; i < n; i += gridDim.x * blockDim.x)
    atomicAdd(&lb[v[i]], 1);
  __syncthreads();
  for (int i = threadIdx.x; i < nb; i += blockDim.x) if (lb[i]) atomicAdd(&bins[i], lb[i]);
}

__global__ void k_hist_glob(const int* __restrict__ v, int n, int* __restrict__ bins){
  for (int i = blockIdx.x * blockDim.x + threadIdx.x; i < n; i += gridDim.x * blockDim.x)
    atomicAdd(&bins[v[i]], 1);
}

// ---------------- scan (exclusive) ----------------
__global__ void k_scan_part(const int* __restrict__ cnt, int n, int* __restrict__ incl, int* __restrict__ bsum){
  __shared__ int s[256];
  int i = blockIdx.x * 256 + threadIdx.x;
  int v = (i < n) ? cnt[i] : 0;
  s[threadIdx.x] = v; __syncthreads();
  for (int off = 1; off < 256; off <<= 1){
    int t = (threadIdx.x >= off) ? s[threadIdx.x - off] : 0;
    __syncthreads();
    s[threadIdx.x] += t;
    __syncthreads();
  }
  if (i < n) incl[i] = s[threadIdx.x];
  if (threadIdx.x == 255) bsum[blockIdx.x] = s[255];
}

__global__ void k_scan_mid(const int* __restrict__ bsum, int nb, int* __restrict__ boff){
  if (threadIdx.x == 0 && blockIdx.x == 0){
    int run = 0;
    for (int b = 0; b < nb; ++b){ boff[b] = run; run += bsum[b]; }
  }
}

__global__ void k_scan_add(const int* __restrict__ incl, const int* __restrict__ cnt,
                           const int* __restrict__ boff, int n,
                           int* __restrict__ rowst, int* __restrict__ cur){
  int i = blockIdx.x * 256 + threadIdx.x;
  if (i < n){
    int v = incl[i] - cnt[i] + boff[blockIdx.x];
    rowst[i] = v; cur[i] = v;
  }
}

// ---------------- CSR scatter ----------------
__global__ void k_scatter_r(const int* __restrict__ dst, const int* __restrict__ src,
                            const int* __restrict__ rv, int n, int* __restrict__ cur,
                            int* __restrict__ colv, int* __restrict__ rvv){
  for (int i = blockIdx.x * blockDim.x + threadIdx.x; i < n; i += gridDim.x * blockDim.x){
    int p = atomicAdd(&cur[dst[i]], 1);
    colv[p] = src[i]; rvv[p] = rv[i];
  }
}

__global__ void k_scatter_m(const int* __restrict__ dst, const int* __restrict__ src,
                            const float* __restrict__ mv, int n, int* __restrict__ cur,
                            int* __restrict__ colv, float* __restrict__ mvv){
  for (int i = blockIdx.x * blockDim.x + threadIdx.x; i < n; i += gridDim.x * blockDim.x){
    int p = atomicAdd(&cur[dst[i]], 1);
    colv[p] = src[i]; mvv[p] = mv[i];
  }
}

// ---------------- transpose+convert: AT[m][k] bf16 from head/tail [k][m] f32 ----------------
// AT is [1024][KP]; rows 1000..1023 and k 50000..KP-1 zero-filled.
__global__ __launch_bounds__(256) void k_prep_at(const float* __restrict__ head,
                                                 const float* __restrict__ tail,
                                                 short* __restrict__ AT){
  __shared__ short Ls[64][68];
  const int k0 = blockIdx.x * 64, m0 = blockIdx.y * 64;
  const int t = threadIdx.x;
  #pragma unroll
  for (int u = 0; u < 4; ++u){
    int kl = (t >> 4) + 16 * u;
    int ml = (t & 15) * 4;
    int kg = k0 + kl, mg = m0 + ml;
    float4 v = {0.f, 0.f, 0.f, 0.f};
    if (kg < NN && mg < 1000){
      v = (mg < RR) ? *(const float4*)(head + (size_t)kg * RR + mg)
                    : *(const float4*)(tail + (size_t)kg * RR + (mg - RR));
    }
    Ls[kl][ml + 0] = f2bf(v.x);
    Ls[kl][ml + 1] = f2bf(v.y);
    Ls[kl][ml + 2] = f2bf(v.z);
    Ls[kl][ml + 3] = f2bf(v.w);
  }
  __syncthreads();
  #pragma unroll
  for (int u = 0; u < 4; ++u){
    int m = (t >> 4) + 16 * u;
    int kq = (t & 15) * 4;
    short4 w = make_short4(Ls[kq][m], Ls[kq + 1][m], Ls[kq + 2][m], Ls[kq + 3][m]);
    *(short4*)(AT + (size_t)(m0 + m) * KP + k0 + kq) = w;
  }
}

// ---------------- generic transpose+convert f32[k][m] -> bf16[m_pad][KPo] ----------------
__global__ __launch_bounds__(256) void k_prep_t(const float* __restrict__ src, int Krows, int Mcols,
                                                short* __restrict__ dst, int KPo){
  __shared__ short Ls[64][68];
  const int k0 = blockIdx.x * 64, m0 = blockIdx.y * 64;
  const int t = threadIdx.x;
  #pragma unroll
  for (int u = 0; u < 4; ++u){
    int kl = (t >> 4) + 16 * u;
    int ml = (t & 15) * 4;
    int kg = k0 + kl, mg = m0 + ml;
    float4 v = {0.f, 0.f, 0.f, 0.f};
    if (kg < Krows && mg < Mcols) v = *(const float4*)(src + (size_t)kg * Mcols + mg);
    Ls[kl][ml + 0] = f2bf(v.x);
    Ls[kl][ml + 1] = f2bf(v.y);
    Ls[kl][ml + 2] = f2bf(v.z);
    Ls[kl][ml + 3] = f2bf(v.w);
  }
  __syncthreads();
  #pragma unroll
  for (int u = 0; u < 4; ++u){
    int m = (t >> 4) + 16 * u;
    int kq = (t & 15) * 4;
    short4 w = make_short4(Ls[kq][m], Ls[kq + 1][m], Ls[kq + 2][m], Ls[kq + 3][m]);
    *(short4*)(dst + (size_t)(m0 + m) * KPo + k0 + kq) = w;
  }
}

// ---------------- compute_r GEMM v2: both operands pre-transposed bf16 [spatial][k] ----------
// acc[m][d] += sum_k AT[m][k] * XT[d][k];  grid (8 m-blocks, 3 n-blocks, 32 k-splits)
__global__ __launch_bounds__(256) void k_gemm_cr2(
    const short* __restrict__ AT, const short* __restrict__ XT, float* __restrict__ acc)
{
  const int m0 = blockIdx.x * 128;
  const int n0 = blockIdx.y * 128;
  const int k0 = blockIdx.z * 1568;

  __shared__ short As[128 * 32];
  __shared__ short Bs[128 * 32];
  const int tid = threadIdx.x;
  const int lane = tid & 63, wave = tid >> 6;
  const int wr = wave >> 1, wc = wave & 1;

  // staging map: chunk c in 0..511 -> row=c>>2, slot=c&3 (16B each); thread does c=tid and c=tid+256
  const int r0 = tid >> 2;
  const int slot = tid & 3;
  const size_t agA = (size_t)(m0 + r0) * KP + slot * 8;
  const size_t agB = (size_t)(m0 + r0 + 64) * KP + slot * 8;
  const size_t bgA = (size_t)(n0 + r0) * KP + slot * 8;
  const size_t bgB = (size_t)(n0 + r0 + 64) * KP + slot * 8;
  short* alA = As + r0 * 32 + slot * 8;
  short* alB = As + (r0 + 64) * 32 + slot * 8;
  short* blA = Bs + r0 * 32 + slot * 8;
  short* blB = Bs + (r0 + 64) * 32 + slot * 8;

  f32x4 c[4][4];
  #pragma unroll
  for (int i = 0; i < 4; ++i)
    #pragma unroll
    for (int j = 0; j < 4; ++j)
      #pragma unroll
      for (int q = 0; q < 4; ++q) c[i][j][q] = 0.f;

  const int krow = (lane >> 4) * 8;
  const int rsel = lane & 15;

  for (int kk = k0; kk < k0 + 1568; kk += 32){
    bf16x8 va0 = *(const bf16x8*)(AT + agA + kk);
    bf16x8 va1 = *(const bf16x8*)(AT + agB + kk);
    bf16x8 vb0 = *(const bf16x8*)(XT + bgA + kk);
    bf16x8 vb1 = *(const bf16x8*)(XT + bgB + kk);
    *(bf16x8*)alA = va0;
    *(bf16x8*)alB = va1;
    *(bf16x8*)blA = vb0;
    *(bf16x8*)blB = vb1;
    __syncthreads();
    bf16x8 af[4], bfr[4];
    #pragma unroll
    for (int i = 0; i < 4; ++i){
      af[i]  = *(const bf16x8*)(As + (wr * 64 + i * 16 + rsel) * 32 + krow);
      bfr[i] = *(const bf16x8*)(Bs + (wc * 64 + i * 16 + rsel) * 32 + krow);
    }
    #pragma unroll
    for (int i = 0; i < 4; ++i)
      #pragma unroll
      for (int j = 0; j < 4; ++j)
        c[i][j] = __builtin_amdgcn_mfma_f32_16x16x32_bf16(af[i], bfr[j], c[i][j], 0, 0, 0);
    __syncthreads();
  }
  const int col = lane & 15;
  const int rw0 = (lane >> 4) * 4;
  #pragma unroll
  for (int j = 0; j < 4; ++j){
    int dg = n0 + wc * 64 + j * 16 + col;
    if (dg >= DD) continue;
    #pragma unroll
    for (int i = 0; i < 4; ++i){
      int mg = m0 + wr * 64 + i * 16 + rw0;
      #pragma unroll
      for (int q = 0; q < 4; ++q)
        if (mg + q < 1000) atomicAdd(acc + (mg + q) * DD + dg, c[i][j][q]);
    }
  }
}

// ---------------- assemble dual_X from acc ----------------
__global__ void k_assemble(const float* __restrict__ acc, const float* __restrict__ hs,
                           const float* __restrict__ ts, float* __restrict__ dualX){
  int i = blockIdx.x * 256 + threadIdx.x;
  if (i < RR * DD){
    int r = i / DD, d = i - r * DD;
    dualX[r * HH + d]      = acc[r * DD + d]          / (hs[r] + 1e-9f);
    dualX[r * HH + DD + d] = acc[(RR + r) * DD + d]   / (ts[r] + 1e-9f);
  }
}

// ---------------- h = feat @ W.T + bias  (f32, [500,600]x[600,600]^T) ----------------
__global__ __launch_bounds__(256) void k_hgemm(const float* __restrict__ feat, const float* __restrict__ W,
                                               const float* __restrict__ bias, float* __restrict__ h){
  __shared__ float Fs[16][17], Ws[16][17];
  int tx = threadIdx.x & 15, ty = threadIdx.x >> 4;
  int r0 = blockIdx.x * 16, j0 = blockIdx.y * 16;
  float acc = 0.f;
  for (int k0 = 0; k0 < HH; k0 += 16){
    int k = k0 + tx;
    Fs[ty][tx] = (r0 + ty < RR && k < HH) ? feat[(r0 + ty) * HH + k] : 0.f;
    Ws[ty][tx] = (j0 + ty < HH && k < HH) ? W[(j0 + ty) * HH + k] : 0.f;
    __syncthreads();
    #pragma unroll
    for (int kk = 0; kk < 16; ++kk) acc += Fs[ty][kk] * Ws[tx][kk];
    __syncthreads();
  }
  int rr = r0 + ty, jj = j0 + tx;
  if (rr < RR && jj < HH) h[rr * HH + jj] = acc + (bias ? bias[jj] : 0.f);
}

// ---------------- per-row dots: f1[r]=h[r]·a1+b1, f2[r]=h[r]·a2+b2 ----------------
__global__ void k_rowdot2(const float* __restrict__ Hm, const float* __restrict__ a1, const float* __restrict__ b1,
                          const float* __restrict__ a2, const float* __restrict__ b2,
                          float* __restrict__ f1, float* __restrict__ f2){
  int wave = threadIdx.x >> 6, lane = threadIdx.x & 63;
  int r = blockIdx.x * 4 + wave;
  if (r >= RR) return;
  float s1 = 0.f, s2 = 0.f;
  for (int k = lane; k < HH; k += 64){
    float hv = Hm[r * HH + k];
    s1 += hv * a1[k];
    if (a2) s2 += hv * a2[k];
  }
  #pragma unroll
  for (int off = 32; off; off >>= 1){
    s1 += __shfl_down(s1, off);
    s2 += __shfl_down(s2, off);
  }
  if (lane == 0){
    f1[r] = s1 + b1[0];
    if (f2) f2[r] = s2 + (b2 ? b2[0] : 0.f);
  }
}

// ---------------- fused dense attention row: softmax + coefs@val + relu ----------------
__global__ __launch_bounds__(512) void k_attrow(const float* __restrict__ f1, const float* __restrict__ f2,
    const float* __restrict__ adj, const float* __restrict__ val, float* __restrict__ outp){
  __shared__ float coef[RR];
  __shared__ float red[512];
  int r = blockIdx.x, t = threadIdx.x;
  float lg = -3.0e38f;
  if (t < RR){
    float l = f1[r] + f2[t];
    l = (l > 0.f) ? l : 0.01f * l;
    if (adj[r * RR + t] <= 0.f) l -= 1e9f;
    lg = l;
  }
  red[t] = lg; __syncthreads();
  for (int off = 256; off; off >>= 1){ if (t < off) red[t] = fmaxf(red[t], red[t + off]); __syncthreads(); }
  float mx = red[0]; __syncthreads();
  float e = (t < RR) ? expf(lg - mx) : 0.f;
  red[t] = e; __syncthreads();
  for (int off = 256; off; off >>= 1){ if (t < off) red[t] += red[t + off]; __syncthreads(); }
  float inv = 1.f / red[0]; __syncthreads();
  if (t < RR) coef[t] = e * inv;
  __syncthreads();
  float acc1 = 0.f, acc2 = 0.f;
  int d2 = t + 512;
  for (int j = 0; j < RR; ++j){
    float cj = coef[j];
    acc1 += cj * val[j * HH + t];
    if (d2 < HH) acc2 += cj * val[j * HH + d2];
  }
  outp[r * HH + t] = fmaxf(acc1, 0.f);
  if (d2 < HH) outp[r * HH + d2] = fmaxf(acc2, 0.f);
}

// ---------------- global-softmax coefficients per relation ----------------
__global__ void k_cvec(const float* __restrict__ tv, const int* __restrict__ cnt, float* __restrict__ cvec){
  __shared__ float red[512];
  int t = threadIdx.x;
  float lr = -3.0e38f, tval = 0.f;
  if (t < RR){
    tval = tv[t];
    tval = (tval > 0.f) ? tval : 0.01f * tval;
    if (cnt[t] > 0) lr = tval;
  }
  red[t] = lr; __syncthreads();
  for (int off = 256; off; off >>= 1){ if (t < off) red[t] = fmaxf(red[t], red[t + off]); __syncthreads(); }
  float mx = red[0]; __syncthreads();
  float ex = (t < RR) ? expf(tval - mx) : 0.f;
  red[t] = (t < RR) ? ex * (float)cnt[t] : 0.f; __syncthreads();
  for (int off = 256; off; off >>= 1){ if (t < off) red[t] += red[t + off]; __syncthreads(); }
  float inv = 1.f / red[0];
  if (t < RR) cvec[t] = ex * inv;
}

// ---------------- sparse att SpMM: out = base + scale*relu(sum c[rv]*X[src]) ----------------
__global__ __launch_bounds__(256) void k_spmm_r(const int* __restrict__ rowst, const int* __restrict__ rowcnt,
    const int* __restrict__ colv, const int* __restrict__ rvv, const float* __restrict__ cvec,
    const float* __restrict__ Xg, const float* __restrict__ base, float scale, float* __restrict__ outp){
  int wave = threadIdx.x >> 6, lane = threadIdx.x & 63;
  int row = blockIdx.x * 4 + wave;
  if (row >= NN) return;
  int st = rowst[row], cn = rowcnt[row];
  float a0 = 0.f, a1 = 0.f, a2 = 0.f, a3 = 0.f, a4 = 0.f;
  for (int e = 0; e < cn; ++e){
    int s = colv[st + e];
    float w = cvec[rvv[st + e]];
    const float* xr = Xg + (size_t)s * DD;
    a0 += w * xr[lane];
    a1 += w * xr[lane + 64];
    a2 += w * xr[lane + 128];
    a3 += w * xr[lane + 192];
    if (lane < 44) a4 += w * xr[lane + 256];
  }
  size_t ro = (size_t)row * DD;
  outp[ro + lane]       = base[ro + lane]       + scale * fmaxf(a0, 0.f);
  outp[ro + lane + 64]  = base[ro + lane + 64]  + scale * fmaxf(a1, 0.f);
  outp[ro + lane + 128] = base[ro + lane + 128] + scale * fmaxf(a2, 0.f);
  outp[ro + lane + 192] = base[ro + lane + 192] + scale * fmaxf(a3, 0.f);
  if (lane < 44) outp[ro + lane + 256] = base[ro + lane + 256] + scale * fmaxf(a4, 0.f);
}

// ---------------- diag-GCN SpMM + highway blend ----------------
__global__ __launch_bounds__(256) void k_spmm_m(const int* __restrict__ rowst, const int* __restrict__ rowcnt,
    const int* __restrict__ colv, const float* __restrict__ mvv,
    const float* __restrict__ Xg, const float* __restrict__ w0, const float* __restrict__ tg,
    const float* __restrict__ base, float* __restrict__ outp){
  int wave = threadIdx.x >> 6, lane = threadIdx.x & 63;
  int row = blockIdx.x * 4 + wave;
  if (row >= NN) return;
  int st = rowst[row], cn = rowcnt[row];
  float a0 = 0.f, a1 = 0.f, a2 = 0.f, a3 = 0.f, a4 = 0.f;
  for (int e = 0; e < cn; ++e){
    int s = colv[st + e];
    float w = mvv[st + e];
    const float* xr = Xg + (size_t)s * DD;
    a0 += w * xr[lane];
    a1 += w * xr[lane + 64];
    a2 += w * xr[lane + 128];
    a3 += w * xr[lane + 192];
    if (lane < 44) a4 += w * xr[lane + 256];
  }
  size_t ro = (size_t)row * DD;
  #pragma unroll
  for (int u = 0; u < 5; ++u){
    int d = lane + u * 64;
    if (d < DD){
      float acc = (u == 0) ? a0 : (u == 1) ? a1 : (u == 2) ? a2 : (u == 3) ? a3 : a4;
      float g = fmaxf(w0[d] * acc, 0.f);
      float tvv = tg[ro + d];
      outp[ro + d] = tvv * g + (1.f - tvv) * base[ro + d];
    }
  }
}

// ---------------- highway gate GEMM v2: Tg = sigmoid(Xin @ Wg + bg) with WgT bf16 ----------
__global__ __launch_bounds__(256) void k_gate2(const float* __restrict__ Xin,
                                               const short* __restrict__ WgT,
                                               const float* __restrict__ bg, float* __restrict__ Tg){
  const int m0 = blockIdx.x * 128, n0 = blockIdx.y * 128;
  __shared__ short As[128 * 32];
  __shared__ short Bs[128 * 32];
  const int tid = threadIdx.x;
  const int lane = tid & 63, wave = tid >> 6;
  const int wr = wave >> 1, wc = wave & 1;

  const int r0 = tid >> 2;
  const int slot = tid & 3;
  const size_t bgA = (size_t)(n0 + r0) * KPW + slot * 8;
  const size_t bgB = (size_t)(n0 + r0 + 64) * KPW + slot * 8;
  short* blA = Bs + r0 * 32 + slot * 8;
  short* blB = Bs + (r0 + 64) * 32 + slot * 8;

  f32x4 c[4][4];
  #pragma unroll
  for (int i = 0; i < 4; ++i)
    #pragma unroll
    for (int j = 0; j < 4; ++j)
      #pragma unroll
      for (int q = 0; q < 4; ++q) c[i][j][q] = 0.f;

  const int krow = (lane >> 4) * 8;
  const int rsel = lane & 15;

  for (int kk = 0; kk < KPW; kk += 32){
    // A: Xin f32 [m][k] k-contiguous -> cvt bf16, write 8B per thread per u (conflict-even)
    #pragma unroll
    for (int u = 0; u < 4; ++u){
      int f4 = tid + u * 256;
      int ml = f4 >> 3;
      int kl = (f4 & 7) * 4;
      int mg = m0 + ml, kg = kk + kl;
      float4 v = {0.f, 0.f, 0.f, 0.f};
      if (mg < NN && kg < DD) v = *(const float4*)(Xin + (size_t)mg * DD + kg);
      ushort4 w = make_ushort4((unsigned short)f2bf(v.x), (unsigned short)f2bf(v.y),
                               (unsigned short)f2bf(v.z), (unsigned short)f2bf(v.w));
      *reinterpret_cast<ushort4*>(&As[ml * 32 + kl]) = w;
    }
    // B: pre-transposed WgT bf16 (padded) -> straight 16B copies
    *(bf16x8*)blA = *(const bf16x8*)(WgT + bgA + kk);
    *(bf16x8*)blB = *(const bf16x8*)(WgT + bgB + kk);
    __syncthreads();
    bf16x8 af[4], bfr[4];
    #pragma unroll
    for (int i = 0; i < 4; ++i){
      af[i]  = *(const bf16x8*)(As + (wr * 64 + i * 16 + rsel) * 32 + krow);
      bfr[i] = *(const bf16x8*)(Bs + (wc * 64 + i * 16 + rsel) * 32 + krow);
    }
    #pragma unroll
    for (int i = 0; i < 4; ++i)
      #pragma unroll
      for (int j = 0; j < 4; ++j)
        c[i][j] = __builtin_amdgcn_mfma_f32_16x16x32_bf16(af[i], bfr[j], c[i][j], 0, 0, 0);
    __syncthreads();
  }
  const int col = lane & 15;
  const int rw0 = (lane >> 4) * 4;
  #pragma unroll
  for (int j = 0; j < 4; ++j){
    int ng = n0 + wc * 64 + j * 16 + col;
    if (ng >= DD) continue;
    float bias = bg[ng];
    #pragma unroll
    for (int i = 0; i < 4; ++i){
      int mg = m0 + wr * 64 + i * 16 + rw0;
      #pragma unroll
      for (int q = 0; q < 4; ++q){
        if (mg + q < NN){
          float x = c[i][j][q] + bias;
          Tg[(size_t)(mg + q) * DD + ng] = 1.f / (1.f + expf(-x));
        }
      }
    }
  }
}

// ================= host =================
extern "C" void kernel_launch(void* const* d_in, const int* in_sizes, int n_in,
                              void* d_out, int out_size, void* d_ws, size_t ws_size,
                              hipStream_t stream)
{
  (void)in_sizes; (void)n_in; (void)out_size; (void)ws_size;
  const float* X0   = (const float*)d_in[0];
  const float* head = (const float*)d_in[1];
  const float* tail = (const float*)d_in[2];
  const float* adj  = (const float*)d_in[3];
  const int*   ridx = (const int*)d_in[4];
  const int*   rval = (const int*)d_in[5];
  const int*   midx = (const int*)d_in[6];
  const float* mval = (const float*)d_in[7];
  const float* W_s  = (const float*)d_in[8];
  const float* a1_s = (const float*)d_in[9];
  const float* b1_s = (const float*)d_in[10];
  const float* a2_s = (const float*)d_in[11];
  const float* b2_s = (const float*)d_in[12];
  const float* w_sp1= (const float*)d_in[13];
  const float* b_sp1= (const float*)d_in[14];
  const float* w_sp2= (const float*)d_in[15];
  const float* b_sp2= (const float*)d_in[16];
  const float* W_d  = (const float*)d_in[17];
  const float* b_d  = (const float*)d_in[18];
  const float* a1_d = (const float*)d_in[19];
  const float* b1_d = (const float*)d_in[20];
  const float* a2_d = (const float*)d_in[21];
  const float* b2_d = (const float*)d_in[22];
  const float* w0_1 = (const float*)d_in[23];
  const float* w0_2 = (const float*)d_in[24];
  const float* Wg1  = (const float*)d_in[25];
  const float* bg1  = (const float*)d_in[26];
  const float* Wg2  = (const float*)d_in[27];
  const float* bg2  = (const float*)d_in[28];

  char* ws = (char*)d_ws;
  size_t off = 0;
  auto alloc = [&](size_t bytes)->char*{
    char* p = ws + off;
    off += (bytes + 255) & ~(size_t)255;
    return p;
  };
  float* acc    = (float*)alloc(1000 * DD * 4);
  float* X1GC   = (float*)alloc((size_t)NN * DD * 4);
  float* X2     = (float*)alloc((size_t)NN * DD * 4);
  float* TG     = (float*)alloc((size_t)NN * DD * 4);   // aliased with XT (lifetimes disjoint)
  float* dualX  = (float*)alloc(RR * HH * 4);
  float* dualH1 = (float*)alloc(RR * HH * 4);
  float* dualH2 = (float*)alloc(RR * HH * 4);
  float* hbuf   = (float*)alloc(RR * HH * 4);
  float* hs     = (float*)alloc(2048);
  float* ts     = (float*)alloc(2048);
  int*   cntR   = (int*)alloc(2048);
  float* f1     = (float*)alloc(2048);
  float* f2     = (float*)alloc(2048);
  float* tv     = (float*)alloc(2048);
  float* cv     = (float*)alloc(2048);
  int* rowcntR  = (int*)alloc((size_t)NN * 4);
  int* rowstR   = (int*)alloc((size_t)NN * 4);
  int* curR     = (int*)alloc((size_t)NN * 4);
  int* colR     = (int*)alloc((size_t)EE * 4);
  int* rvR      = (int*)alloc((size_t)EE * 4);
  int* rowcntM  = (int*)alloc((size_t)NN * 4);
  int* rowstM   = (int*)alloc((size_t)NN * 4);
  int* curM     = (int*)alloc((size_t)NN * 4);
  int* colM     = (int*)alloc((size_t)EE * 4);
  float* mvM    = (float*)alloc((size_t)EE * 4);
  int* incl     = (int*)alloc((size_t)NN * 4);
  int* bsum     = (int*)alloc(1024);
  int* boff     = (int*)alloc(1024);
  short* WgT1   = (short*)alloc((size_t)384 * KPW * 2);
  short* WgT2   = (short*)alloc((size_t)384 * KPW * 2);
  short* AT     = (short*)alloc((size_t)1024 * KP * 2);   // 102.8 MB, built once

  short* XT = (short*)TG;   // 384*KP*2 = 38.5 MB fits in TG's 60 MB region

  float* OUT0 = (float*)d_out;
  float* OUT1 = (float*)d_out + (size_t)NN * DD;

  hipMemsetAsync(hs, 0, 3 * 2048, stream);
  hipMemsetAsync(rowcntR, 0, (size_t)NN * 4, stream);
  hipMemsetAsync(rowcntM, 0, (size_t)NN * 4, stream);

  // ---- static prep ----
  k_colsum<<<dim3(196, 2), 512, 0, stream>>>(head, tail, hs, ts);
  k_hist_lds<<<256, 256, RR * 4, stream>>>(rval, EE, RR, cntR);
  k_hist_glob<<<512, 256, 0, stream>>>(ridx, EE, rowcntR);
  k_scan_part<<<196, 256, 0, stream>>>(rowcntR, NN, incl, bsum);
  k_scan_mid<<<1, 1, 0, stream>>>(bsum, 196, boff);
  k_scan_add<<<196, 256, 0, stream>>>(incl, rowcntR, boff, NN, rowstR, curR);
  k_scatter_r<<<512, 256, 0, stream>>>(ridx, ridx + EE, rval, EE, curR, colR, rvR);
  k_hist_glob<<<512, 256, 0, stream>>>(midx, EE, rowcntM);
  k_scan_part<<<196, 256, 0, stream>>>(rowcntM, NN, incl, bsum);
  k_scan_mid<<<1, 1, 0, stream>>>(bsum, 196, boff);
  k_scan_add<<<196, 256, 0, stream>>>(incl, rowcntM, boff, NN, rowstM, curM);
  k_scatter_m<<<512, 256, 0, stream>>>(midx, midx + EE, mval, EE, curM, colM, mvM);
  k_prep_at<<<dim3(784, 16), 256, 0, stream>>>(head, tail, AT);
  k_prep_t<<<dim3(5, 6), 256, 0, stream>>>(Wg1, DD, DD, WgT1, KPW);
  k_prep_t<<<dim3(5, 6), 256, 0, stream>>>(Wg2, DD, DD, WgT2, KPW);

  // ---- round 1 ----
  hipMemsetAsync(acc, 0, 1000 * DD * 4, stream);
  k_prep_t<<<dim3(784, 6), 256, 0, stream>>>(X0, NN, DD, XT, KP);
  k_gemm_cr2<<<dim3(8, 3, 32), 256, 0, stream>>>(AT, XT, acc);
  k_assemble<<<586, 256, 0, stream>>>(acc, hs, ts, dualX);
  k_hgemm<<<dim3(32, 38), 256, 0, stream>>>(dualX, W_s, nullptr, hbuf);
  k_rowdot2<<<125, 256, 0, stream>>>(hbuf, a1_s, b1_s, a2_s, b2_s, f1, f2);
  k_attrow<<<500, 512, 0, stream>>>(f1, f2, adj, dualX, dualH1);
  k_rowdot2<<<125, 256, 0, stream>>>(dualH1, w_sp1, b_sp1, nullptr, nullptr, tv, nullptr);
  k_cvec<<<1, 512, 0, stream>>>(tv, cntR, cv);
  k_spmm_r<<<12500, 256, 0, stream>>>(rowstR, rowcntR, colR, rvR, cv, X0, X0, 0.1f, X1GC);

  // ---- round 2 ----
  hipMemsetAsync(acc, 0, 1000 * DD * 4, stream);
  k_prep_t<<<dim3(784, 6), 256, 0, stream>>>(X1GC, NN, DD, XT, KP);
  k_gemm_cr2<<<dim3(8, 3, 32), 256, 0, stream>>>(AT, XT, acc);
  k_assemble<<<586, 256, 0, stream>>>(acc, hs, ts, dualX);
  k_hgemm<<<dim3(32, 38), 256, 0, stream>>>(dualX, W_d, b_d, hbuf);
  k_rowdot2<<<125, 256, 0, stream>>>(hbuf, a1_d, b1_d, a2_d, b2_d, f1, f2);
  k_attrow<<<500, 512, 0, stream>>>(f1, f2, adj, dualH1, dualH2);
  k_rowdot2<<<125, 256, 0, stream>>>(dualH2, w_sp2, b_sp2, nullptr, nullptr, tv, nullptr);
  k_cvec<<<1, 512, 0, stream>>>(tv, cntR, cv);
  k_spmm_r<<<12500, 256, 0, stream>>>(rowstR, rowcntR, colR, rvR, cv, X1GC, X0, 0.3f, X2);

  // ---- GCN + highway (TG region free of XT now; gemm2 already consumed XT) ----
  k_gate2<<<dim3(391, 3), 256, 0, stream>>>(X2, WgT1, bg1, TG);
  k_spmm_m<<<12500, 256, 0, stream>>>(rowstM, rowcntM, colM, mvM, X2, w0_1, TG, X2, X1GC);
  k_gate2<<<dim3(391, 3), 256, 0, stream>>>(X1GC, WgT2, bg2, TG);
  k_spmm_m<<<12500, 256, 0, stream>>>(rowstM, rowcntM, colM, mvM, X1GC, w0_2, TG, X1GC, OUT0);

  // ---- round 3 (dual only; XT overwrites TG region after last spmm_m read) ----
  hipMemsetAsync(acc, 0, 1000 * DD * 4, stream);
  k_prep_t<<<dim3(784, 6), 256, 0, stream>>>(OUT0, NN, DD, XT, KP);
  k_gemm_cr2<<<dim3(8, 3, 32), 256, 0, stream>>>(AT, XT, acc);
  k_assemble<<<586, 256, 0, stream>>>(acc, hs, ts, dualX);
  k_hgemm<<<dim3(32, 38), 256, 0, stream>>>(dualX, W_d, b_d, hbuf);
  k_rowdot2<<<125, 256, 0, stream>>>(hbuf, a1_d, b1_d, a2_d, b2_d, f1, f2);
  k_attrow<<<500, 512, 0, stream>>>(f1, f2, adj, dualH2, OUT1);
}

// Round 6
// 1979.207 us; speedup vs baseline: 1.4842x; 1.1762x over previous
//
#include <hip/hip_runtime.h>
#include <hip/hip_bf16.h>

#define NN 50000
#define RR 500
#define DD 300
#define HH 600
#define EE 500000
#define KP 50176      // 50000 padded to multiple of 32 (32 k-splits x 1568)
#define KPW 320       // 300 padded to multiple of 32 (gate GEMM K)

typedef short bf16x8 __attribute__((ext_vector_type(8)));
typedef float f32x4  __attribute__((ext_vector_type(4)));

__device__ __forceinline__ short f2bf(float f){
  union { float f; unsigned u; } v; v.f = f;
  unsigned r = v.u + 0x7fffu + ((v.u >> 16) & 1u);   // RNE
  return (short)(r >> 16);
}

// ---------------- colsum of head_r / tail_r ----------------
__global__ void k_colsum(const float* __restrict__ head, const float* __restrict__ tail,
                         float* __restrict__ hs, float* __restrict__ ts){
  const float* src = blockIdx.y ? tail : head;
  float* dst = blockIdx.y ? ts : hs;
  int t = threadIdx.x;
  int r0 = blockIdx.x * 256;
  int r1 = r0 + 256; if (r1 > NN) r1 = NN;
  if (t < RR){
    float a = 0.f;
    for (int r = r0; r < r1; ++r) a += src[r * RR + t];
    atomicAdd(&dst[t], a);
  }
}

// ---------------- histograms ----------------
__global__ void k_hist_lds(const int* __restrict__ v, int n, int nb, int* __restrict__ bins){
  extern __shared__ int lb[];
  for (int i = threadIdx.x; i < nb; i += blockDim.x) lb[i] = 0;
  __syncthreads();
  for (int i = blockIdx.x * blockDim.x + threadIdx.x; i < n; i += gridDim.x * blockDim.x)
    atomicAdd(&lb[v[i]], 1);
  __syncthreads();
  for (int i = threadIdx.x; i < nb; i += blockDim.x) if (lb[i]) atomicAdd(&bins[i], lb[i]);
}

__global__ void k_hist_glob(const int* __restrict__ v, int n, int* __restrict__ bins){
  for (int i = blockIdx.x * blockDim.x + threadIdx.x; i < n; i += gridDim.x * blockDim.x)
    atomicAdd(&bins[v[i]], 1);
}

// ---------------- scan (exclusive) ----------------
__global__ void k_scan_part(const int* __restrict__ cnt, int n, int* __restrict__ incl, int* __restrict__ bsum){
  __shared__ int s[256];
  int i = blockIdx.x * 256 + threadIdx.x;
  int v = (i < n) ? cnt[i] : 0;
  s[threadIdx.x] = v; __syncthreads();
  for (int off = 1; off < 256; off <<= 1){
    int t = (threadIdx.x >= off) ? s[threadIdx.x - off] : 0;
    __syncthreads();
    s[threadIdx.x] += t;
    __syncthreads();
  }
  if (i < n) incl[i] = s[threadIdx.x];
  if (threadIdx.x == 255) bsum[blockIdx.x] = s[255];
}

__global__ void k_scan_mid(const int* __restrict__ bsum, int nb, int* __restrict__ boff){
  if (threadIdx.x == 0 && blockIdx.x == 0){
    int run = 0;
    for (int b = 0; b < nb; ++b){ boff[b] = run; run += bsum[b]; }
  }
}

__global__ void k_scan_add(const int* __restrict__ incl, const int* __restrict__ cnt,
                           const int* __restrict__ boff, int n,
                           int* __restrict__ rowst, int* __restrict__ cur){
  int i = blockIdx.x * 256 + threadIdx.x;
  if (i < n){
    int v = incl[i] - cnt[i] + boff[blockIdx.x];
    rowst[i] = v; cur[i] = v;
  }
}

// ---------------- CSR scatter ----------------
__global__ void k_scatter_r(const int* __restrict__ dst, const int* __restrict__ src,
                            const int* __restrict__ rv, int n, int* __restrict__ cur,
                            int* __restrict__ colv, int* __restrict__ rvv){
  for (int i = blockIdx.x * blockDim.x + threadIdx.x; i < n; i += gridDim.x * blockDim.x){
    int p = atomicAdd(&cur[dst[i]], 1);
    colv[p] = src[i]; rvv[p] = rv[i];
  }
}

__global__ void k_scatter_m(const int* __restrict__ dst, const int* __restrict__ src,
                            const float* __restrict__ mv, int n, int* __restrict__ cur,
                            int* __restrict__ colv, float* __restrict__ mvv){
  for (int i = blockIdx.x * blockDim.x + threadIdx.x; i < n; i += gridDim.x * blockDim.x){
    int p = atomicAdd(&cur[dst[i]], 1);
    colv[p] = src[i]; mvv[p] = mv[i];
  }
}

// ---------------- transpose+convert: AT[m][k] bf16 from head/tail [k][m] f32 ----------------
__global__ __launch_bounds__(256) void k_prep_at(const float* __restrict__ head,
                                                 const float* __restrict__ tail,
                                                 short* __restrict__ AT){
  __shared__ short Ls[64][68];
  const int k0 = blockIdx.x * 64, m0 = blockIdx.y * 64;
  const int t = threadIdx.x;
  #pragma unroll
  for (int u = 0; u < 4; ++u){
    int kl = (t >> 4) + 16 * u;
    int ml = (t & 15) * 4;
    int kg = k0 + kl, mg = m0 + ml;
    float4 v = {0.f, 0.f, 0.f, 0.f};
    if (kg < NN && mg < 1000){
      v = (mg < RR) ? *(const float4*)(head + (size_t)kg * RR + mg)
                    : *(const float4*)(tail + (size_t)kg * RR + (mg - RR));
    }
    Ls[kl][ml + 0] = f2bf(v.x);
    Ls[kl][ml + 1] = f2bf(v.y);
    Ls[kl][ml + 2] = f2bf(v.z);
    Ls[kl][ml + 3] = f2bf(v.w);
  }
  __syncthreads();
  #pragma unroll
  for (int u = 0; u < 4; ++u){
    int m = (t >> 4) + 16 * u;
    int kq = (t & 15) * 4;
    short4 w = make_short4(Ls[kq][m], Ls[kq + 1][m], Ls[kq + 2][m], Ls[kq + 3][m]);
    *(short4*)(AT + (size_t)(m0 + m) * KP + k0 + kq) = w;
  }
}

// ---------------- generic transpose+convert f32[k][m] -> bf16[m_pad][KPo] ----------------
__global__ __launch_bounds__(256) void k_prep_t(const float* __restrict__ src, int Krows, int Mcols,
                                                short* __restrict__ dst, int KPo){
  __shared__ short Ls[64][68];
  const int k0 = blockIdx.x * 64, m0 = blockIdx.y * 64;
  const int t = threadIdx.x;
  #pragma unroll
  for (int u = 0; u < 4; ++u){
    int kl = (t >> 4) + 16 * u;
    int ml = (t & 15) * 4;
    int kg = k0 + kl, mg = m0 + ml;
    float4 v = {0.f, 0.f, 0.f, 0.f};
    if (kg < Krows && mg < Mcols) v = *(const float4*)(src + (size_t)kg * Mcols + mg);
    Ls[kl][ml + 0] = f2bf(v.x);
    Ls[kl][ml + 1] = f2bf(v.y);
    Ls[kl][ml + 2] = f2bf(v.z);
    Ls[kl][ml + 3] = f2bf(v.w);
  }
  __syncthreads();
  #pragma unroll
  for (int u = 0; u < 4; ++u){
    int m = (t >> 4) + 16 * u;
    int kq = (t & 15) * 4;
    short4 w = make_short4(Ls[kq][m], Ls[kq + 1][m], Ls[kq + 2][m], Ls[kq + 3][m]);
    *(short4*)(dst + (size_t)(m0 + m) * KPo + k0 + kq) = w;
  }
}

// ---------------- compute_r GEMM v2: both operands pre-transposed bf16 [spatial][k] ----------
__global__ __launch_bounds__(256) void k_gemm_cr2(
    const short* __restrict__ AT, const short* __restrict__ XT, float* __restrict__ acc)
{
  const int m0 = blockIdx.x * 128;
  const int n0 = blockIdx.y * 128;
  const int k0 = blockIdx.z * 1568;

  __shared__ short As[128 * 32];
  __shared__ short Bs[128 * 32];
  const int tid = threadIdx.x;
  const int lane = tid & 63, wave = tid >> 6;
  const int wr = wave >> 1, wc = wave & 1;

  const int r0 = tid >> 2;
  const int slot = tid & 3;
  const size_t agA = (size_t)(m0 + r0) * KP + slot * 8;
  const size_t agB = (size_t)(m0 + r0 + 64) * KP + slot * 8;
  const size_t bgA = (size_t)(n0 + r0) * KP + slot * 8;
  const size_t bgB = (size_t)(n0 + r0 + 64) * KP + slot * 8;
  short* alA = As + r0 * 32 + slot * 8;
  short* alB = As + (r0 + 64) * 32 + slot * 8;
  short* blA = Bs + r0 * 32 + slot * 8;
  short* blB = Bs + (r0 + 64) * 32 + slot * 8;

  f32x4 c[4][4];
  #pragma unroll
  for (int i = 0; i < 4; ++i)
    #pragma unroll
    for (int j = 0; j < 4; ++j)
      #pragma unroll
      for (int q = 0; q < 4; ++q) c[i][j][q] = 0.f;

  const int krow = (lane >> 4) * 8;
  const int rsel = lane & 15;

  for (int kk = k0; kk < k0 + 1568; kk += 32){
    bf16x8 va0 = *(const bf16x8*)(AT + agA + kk);
    bf16x8 va1 = *(const bf16x8*)(AT + agB + kk);
    bf16x8 vb0 = *(const bf16x8*)(XT + bgA + kk);
    bf16x8 vb1 = *(const bf16x8*)(XT + bgB + kk);
    *(bf16x8*)alA = va0;
    *(bf16x8*)alB = va1;
    *(bf16x8*)blA = vb0;
    *(bf16x8*)blB = vb1;
    __syncthreads();
    bf16x8 af[4], bfr[4];
    #pragma unroll
    for (int i = 0; i < 4; ++i){
      af[i]  = *(const bf16x8*)(As + (wr * 64 + i * 16 + rsel) * 32 + krow);
      bfr[i] = *(const bf16x8*)(Bs + (wc * 64 + i * 16 + rsel) * 32 + krow);
    }
    #pragma unroll
    for (int i = 0; i < 4; ++i)
      #pragma unroll
      for (int j = 0; j < 4; ++j)
        c[i][j] = __builtin_amdgcn_mfma_f32_16x16x32_bf16(af[i], bfr[j], c[i][j], 0, 0, 0);
    __syncthreads();
  }
  const int col = lane & 15;
  const int rw0 = (lane >> 4) * 4;
  #pragma unroll
  for (int j = 0; j < 4; ++j){
    int dg = n0 + wc * 64 + j * 16 + col;
    if (dg >= DD) continue;
    #pragma unroll
    for (int i = 0; i < 4; ++i){
      int mg = m0 + wr * 64 + i * 16 + rw0;
      #pragma unroll
      for (int q = 0; q < 4; ++q)
        if (mg + q < 1000) atomicAdd(acc + (mg + q) * DD + dg, c[i][j][q]);
    }
  }
}

// ---------------- assemble dual_X from acc ----------------
__global__ void k_assemble(const float* __restrict__ acc, const float* __restrict__ hs,
                           const float* __restrict__ ts, float* __restrict__ dualX){
  int i = blockIdx.x * 256 + threadIdx.x;
  if (i < RR * DD){
    int r = i / DD, d = i - r * DD;
    dualX[r * HH + d]      = acc[r * DD + d]          / (hs[r] + 1e-9f);
    dualX[r * HH + DD + d] = acc[(RR + r) * DD + d]   / (ts[r] + 1e-9f);
  }
}

// ---------------- h = feat @ W.T + bias  (f32, [500,600]x[600,600]^T) ----------------
__global__ __launch_bounds__(256) void k_hgemm(const float* __restrict__ feat, const float* __restrict__ W,
                                               const float* __restrict__ bias, float* __restrict__ h){
  __shared__ float Fs[16][17], Ws[16][17];
  int tx = threadIdx.x & 15, ty = threadIdx.x >> 4;
  int r0 = blockIdx.x * 16, j0 = blockIdx.y * 16;
  float acc = 0.f;
  for (int k0 = 0; k0 < HH; k0 += 16){
    int k = k0 + tx;
    Fs[ty][tx] = (r0 + ty < RR && k < HH) ? feat[(r0 + ty) * HH + k] : 0.f;
    Ws[ty][tx] = (j0 + ty < HH && k < HH) ? W[(j0 + ty) * HH + k] : 0.f;
    __syncthreads();
    #pragma unroll
    for (int kk = 0; kk < 16; ++kk) acc += Fs[ty][kk] * Ws[tx][kk];
    __syncthreads();
  }
  int rr = r0 + ty, jj = j0 + tx;
  if (rr < RR && jj < HH) h[rr * HH + jj] = acc + (bias ? bias[jj] : 0.f);
}

// ---------------- per-row dots: f1[r]=h[r]·a1+b1, f2[r]=h[r]·a2+b2 ----------------
__global__ void k_rowdot2(const float* __restrict__ Hm, const float* __restrict__ a1, const float* __restrict__ b1,
                          const float* __restrict__ a2, const float* __restrict__ b2,
                          float* __restrict__ f1, float* __restrict__ f2){
  int wave = threadIdx.x >> 6, lane = threadIdx.x & 63;
  int r = blockIdx.x * 4 + wave;
  if (r >= RR) return;
  float s1 = 0.f, s2 = 0.f;
  for (int k = lane; k < HH; k += 64){
    float hv = Hm[r * HH + k];
    s1 += hv * a1[k];
    if (a2) s2 += hv * a2[k];
  }
  #pragma unroll
  for (int off = 32; off; off >>= 1){
    s1 += __shfl_down(s1, off);
    s2 += __shfl_down(s2, off);
  }
  if (lane == 0){
    f1[r] = s1 + b1[0];
    if (f2) f2[r] = s2 + (b2 ? b2[0] : 0.f);
  }
}

// ---------------- fused dense attention, 8 rows/block, val-load amortized ----------------
// grid (63, 2): 8 rows x 300-col half per block; 320 threads (5 waves).
__global__ __launch_bounds__(320) void k_attrow2(const float* __restrict__ f1, const float* __restrict__ f2,
    const float* __restrict__ adj, const float* __restrict__ val, float* __restrict__ outp){
  __shared__ float coef[8][504];
  const int r0 = blockIdx.x * 8;
  const int t = threadIdx.x;
  const int wave = t >> 6, lane = t & 63;

  // Phase 1: waves 0..3 compute softmax for 2 rows each, wave-local (shfl reductions)
  if (wave < 4){
    #pragma unroll
    for (int sub = 0; sub < 2; ++sub){
      const int slot = wave * 2 + sub;
      const int r = r0 + slot;
      if (r < RR){
        const float f1r = f1[r];
        float lg[8];
        float mx = -3.0e38f;
        #pragma unroll
        for (int cI = 0; cI < 8; ++cI){
          int j = lane + 64 * cI;
          float l = -3.0e38f;
          if (j < RR){
            l = f1r + f2[j];
            l = (l > 0.f) ? l : 0.01f * l;
            if (adj[r * RR + j] <= 0.f) l -= 1e9f;
          }
          lg[cI] = l;
          mx = fmaxf(mx, l);
        }
        #pragma unroll
        for (int off = 32; off; off >>= 1) mx = fmaxf(mx, __shfl_xor(mx, off));
        float sum = 0.f;
        float ev[8];
        #pragma unroll
        for (int cI = 0; cI < 8; ++cI){
          int j = lane + 64 * cI;
          float e = (j < RR) ? expf(lg[cI] - mx) : 0.f;
          ev[cI] = e;
          sum += e;
        }
        #pragma unroll
        for (int off = 32; off; off >>= 1) sum += __shfl_xor(sum, off);
        float inv = 1.f / sum;
        #pragma unroll
        for (int cI = 0; cI < 8; ++cI){
          int j = lane + 64 * cI;
          if (j < RR) coef[slot][j] = ev[cI] * inv;
        }
      } else {
        // zero stale LDS so phase-2 FMAs on unused rows stay finite
        #pragma unroll
        for (int cI = 0; cI < 8; ++cI){
          int j = lane + 64 * cI;
          if (j < RR) coef[slot][j] = 0.f;
        }
      }
    }
  }
  __syncthreads();

  // Phase 2: thread t owns one output column; 8-row register accumulators
  if (t < 300){
    const int col = blockIdx.y * 300 + t;
    float acc[8];
    #pragma unroll
    for (int rI = 0; rI < 8; ++rI) acc[rI] = 0.f;
    for (int j = 0; j < RR; j += 4){
      float v0 = val[(j + 0) * HH + col];
      float v1 = val[(j + 1) * HH + col];
      float v2 = val[(j + 2) * HH + col];
      float v3 = val[(j + 3) * HH + col];
      #pragma unroll
      for (int rI = 0; rI < 8; ++rI){
        f32x4 cf = *(const f32x4*)&coef[rI][j];
        acc[rI] += cf[0] * v0 + cf[1] * v1 + cf[2] * v2 + cf[3] * v3;
      }
    }
    #pragma unroll
    for (int rI = 0; rI < 8; ++rI){
      int r = r0 + rI;
      if (r < RR) outp[r * HH + col] = fmaxf(acc[rI], 0.f);
    }
  }
}

// ---------------- global-softmax coefficients per relation ----------------
__global__ void k_cvec(const float* __restrict__ tv, const int* __restrict__ cnt, float* __restrict__ cvec){
  __shared__ float red[512];
  int t = threadIdx.x;
  float lr = -3.0e38f, tval = 0.f;
  if (t < RR){
    tval = tv[t];
    tval = (tval > 0.f) ? tval : 0.01f * tval;
    if (cnt[t] > 0) lr = tval;
  }
  red[t] = lr; __syncthreads();
  for (int off = 256; off; off >>= 1){ if (t < off) red[t] = fmaxf(red[t], red[t + off]); __syncthreads(); }
  float mx = red[0]; __syncthreads();
  float ex = (t < RR) ? expf(tval - mx) : 0.f;
  red[t] = (t < RR) ? ex * (float)cnt[t] : 0.f; __syncthreads();
  for (int off = 256; off; off >>= 1){ if (t < off) red[t] += red[t + off]; __syncthreads(); }
  float inv = 1.f / red[0];
  if (t < RR) cvec[t] = ex * inv;
}

// ---------------- sparse att SpMM: out = base + scale*relu(sum c[rv]*X[src]) ----------------
__global__ __launch_bounds__(256) void k_spmm_r(const int* __restrict__ rowst, const int* __restrict__ rowcnt,
    const int* __restrict__ colv, const int* __restrict__ rvv, const float* __restrict__ cvec,
    const float* __restrict__ Xg, const float* __restrict__ base, float scale, float* __restrict__ outp){
  int wave = threadIdx.x >> 6, lane = threadIdx.x & 63;
  int row = blockIdx.x * 4 + wave;
  if (row >= NN) return;
  int st = rowst[row], cn = rowcnt[row];
  float a0 = 0.f, a1 = 0.f, a2 = 0.f, a3 = 0.f, a4 = 0.f;
  for (int e = 0; e < cn; ++e){
    int s = colv[st + e];
    float w = cvec[rvv[st + e]];
    const float* xr = Xg + (size_t)s * DD;
    a0 += w * xr[lane];
    a1 += w * xr[lane + 64];
    a2 += w * xr[lane + 128];
    a3 += w * xr[lane + 192];
    if (lane < 44) a4 += w * xr[lane + 256];
  }
  size_t ro = (size_t)row * DD;
  outp[ro + lane]       = base[ro + lane]       + scale * fmaxf(a0, 0.f);
  outp[ro + lane + 64]  = base[ro + lane + 64]  + scale * fmaxf(a1, 0.f);
  outp[ro + lane + 128] = base[ro + lane + 128] + scale * fmaxf(a2, 0.f);
  outp[ro + lane + 192] = base[ro + lane + 192] + scale * fmaxf(a3, 0.f);
  if (lane < 44) outp[ro + lane + 256] = base[ro + lane + 256] + scale * fmaxf(a4, 0.f);
}

// ---------------- diag-GCN SpMM + highway blend ----------------
__global__ __launch_bounds__(256) void k_spmm_m(const int* __restrict__ rowst, const int* __restrict__ rowcnt,
    const int* __restrict__ colv, const float* __restrict__ mvv,
    const float* __restrict__ Xg, const float* __restrict__ w0, const float* __restrict__ tg,
    const float* __restrict__ base, float* __restrict__ outp){
  int wave = threadIdx.x >> 6, lane = threadIdx.x & 63;
  int row = blockIdx.x * 4 + wave;
  if (row >= NN) return;
  int st = rowst[row], cn = rowcnt[row];
  float a0 = 0.f, a1 = 0.f, a2 = 0.f, a3 = 0.f, a4 = 0.f;
  for (int e = 0; e < cn; ++e){
    int s = colv[st + e];
    float w = mvv[st + e];
    const float* xr = Xg + (size_t)s * DD;
    a0 += w * xr[lane];
    a1 += w * xr[lane + 64];
    a2 += w * xr[lane + 128];
    a3 += w * xr[lane + 192];
    if (lane < 44) a4 += w * xr[lane + 256];
  }
  size_t ro = (size_t)row * DD;
  #pragma unroll
  for (int u = 0; u < 5; ++u){
    int d = lane + u * 64;
    if (d < DD){
      float acc = (u == 0) ? a0 : (u == 1) ? a1 : (u == 2) ? a2 : (u == 3) ? a3 : a4;
      float g = fmaxf(w0[d] * acc, 0.f);
      float tvv = tg[ro + d];
      outp[ro + d] = tvv * g + (1.f - tvv) * base[ro + d];
    }
  }
}

// ---------------- highway gate GEMM v2: Tg = sigmoid(Xin @ Wg + bg) with WgT bf16 ----------
__global__ __launch_bounds__(256) void k_gate2(const float* __restrict__ Xin,
                                               const short* __restrict__ WgT,
                                               const float* __restrict__ bg, float* __restrict__ Tg){
  const int m0 = blockIdx.x * 128, n0 = blockIdx.y * 128;
  __shared__ short As[128 * 32];
  __shared__ short Bs[128 * 32];
  const int tid = threadIdx.x;
  const int lane = tid & 63, wave = tid >> 6;
  const int wr = wave >> 1, wc = wave & 1;

  const int r0 = tid >> 2;
  const int slot = tid & 3;
  const size_t bgA = (size_t)(n0 + r0) * KPW + slot * 8;
  const size_t bgB = (size_t)(n0 + r0 + 64) * KPW + slot * 8;
  short* blA = Bs + r0 * 32 + slot * 8;
  short* blB = Bs + (r0 + 64) * 32 + slot * 8;

  f32x4 c[4][4];
  #pragma unroll
  for (int i = 0; i < 4; ++i)
    #pragma unroll
    for (int j = 0; j < 4; ++j)
      #pragma unroll
      for (int q = 0; q < 4; ++q) c[i][j][q] = 0.f;

  const int krow = (lane >> 4) * 8;
  const int rsel = lane & 15;

  for (int kk = 0; kk < KPW; kk += 32){
    #pragma unroll
    for (int u = 0; u < 4; ++u){
      int f4 = tid + u * 256;
      int ml = f4 >> 3;
      int kl = (f4 & 7) * 4;
      int mg = m0 + ml, kg = kk + kl;
      float4 v = {0.f, 0.f, 0.f, 0.f};
      if (mg < NN && kg < DD) v = *(const float4*)(Xin + (size_t)mg * DD + kg);
      ushort4 w = make_ushort4((unsigned short)f2bf(v.x), (unsigned short)f2bf(v.y),
                               (unsigned short)f2bf(v.z), (unsigned short)f2bf(v.w));
      *reinterpret_cast<ushort4*>(&As[ml * 32 + kl]) = w;
    }
    *(bf16x8*)blA = *(const bf16x8*)(WgT + bgA + kk);
    *(bf16x8*)blB = *(const bf16x8*)(WgT + bgB + kk);
    __syncthreads();
    bf16x8 af[4], bfr[4];
    #pragma unroll
    for (int i = 0; i < 4; ++i){
      af[i]  = *(const bf16x8*)(As + (wr * 64 + i * 16 + rsel) * 32 + krow);
      bfr[i] = *(const bf16x8*)(Bs + (wc * 64 + i * 16 + rsel) * 32 + krow);
    }
    #pragma unroll
    for (int i = 0; i < 4; ++i)
      #pragma unroll
      for (int j = 0; j < 4; ++j)
        c[i][j] = __builtin_amdgcn_mfma_f32_16x16x32_bf16(af[i], bfr[j], c[i][j], 0, 0, 0);
    __syncthreads();
  }
  const int col = lane & 15;
  const int rw0 = (lane >> 4) * 4;
  #pragma unroll
  for (int j = 0; j < 4; ++j){
    int ng = n0 + wc * 64 + j * 16 + col;
    if (ng >= DD) continue;
    float bias = bg[ng];
    #pragma unroll
    for (int i = 0; i < 4; ++i){
      int mg = m0 + wr * 64 + i * 16 + rw0;
      #pragma unroll
      for (int q = 0; q < 4; ++q){
        if (mg + q < NN){
          float x = c[i][j][q] + bias;
          Tg[(size_t)(mg + q) * DD + ng] = 1.f / (1.f + expf(-x));
        }
      }
    }
  }
}

// ================= host =================
extern "C" void kernel_launch(void* const* d_in, const int* in_sizes, int n_in,
                              void* d_out, int out_size, void* d_ws, size_t ws_size,
                              hipStream_t stream)
{
  (void)in_sizes; (void)n_in; (void)out_size; (void)ws_size;
  const float* X0   = (const float*)d_in[0];
  const float* head = (const float*)d_in[1];
  const float* tail = (const float*)d_in[2];
  const float* adj  = (const float*)d_in[3];
  const int*   ridx = (const int*)d_in[4];
  const int*   rval = (const int*)d_in[5];
  const int*   midx = (const int*)d_in[6];
  const float* mval = (const float*)d_in[7];
  const float* W_s  = (const float*)d_in[8];
  const float* a1_s = (const float*)d_in[9];
  const float* b1_s = (const float*)d_in[10];
  const float* a2_s = (const float*)d_in[11];
  const float* b2_s = (const float*)d_in[12];
  const float* w_sp1= (const float*)d_in[13];
  const float* b_sp1= (const float*)d_in[14];
  const float* w_sp2= (const float*)d_in[15];
  const float* b_sp2= (const float*)d_in[16];
  const float* W_d  = (const float*)d_in[17];
  const float* b_d  = (const float*)d_in[18];
  const float* a1_d = (const float*)d_in[19];
  const float* b1_d = (const float*)d_in[20];
  const float* a2_d = (const float*)d_in[21];
  const float* b2_d = (const float*)d_in[22];
  const float* w0_1 = (const float*)d_in[23];
  const float* w0_2 = (const float*)d_in[24];
  const float* Wg1  = (const float*)d_in[25];
  const float* bg1  = (const float*)d_in[26];
  const float* Wg2  = (const float*)d_in[27];
  const float* bg2  = (const float*)d_in[28];

  char* ws = (char*)d_ws;
  size_t off = 0;
  auto alloc = [&](size_t bytes)->char*{
    char* p = ws + off;
    off += (bytes + 255) & ~(size_t)255;
    return p;
  };
  float* acc    = (float*)alloc(1000 * DD * 4);
  float* X1GC   = (float*)alloc((size_t)NN * DD * 4);
  float* X2     = (float*)alloc((size_t)NN * DD * 4);
  float* TG     = (float*)alloc((size_t)NN * DD * 4);   // aliased with XT (lifetimes disjoint)
  float* dualX  = (float*)alloc(RR * HH * 4);
  float* dualH1 = (float*)alloc(RR * HH * 4);
  float* dualH2 = (float*)alloc(RR * HH * 4);
  float* hbuf   = (float*)alloc(RR * HH * 4);
  float* hs     = (float*)alloc(2048);
  float* ts     = (float*)alloc(2048);
  int*   cntR   = (int*)alloc(2048);
  float* f1     = (float*)alloc(2048);
  float* f2     = (float*)alloc(2048);
  float* tv     = (float*)alloc(2048);
  float* cv     = (float*)alloc(2048);
  int* rowcntR  = (int*)alloc((size_t)NN * 4);
  int* rowstR   = (int*)alloc((size_t)NN * 4);
  int* curR     = (int*)alloc((size_t)NN * 4);
  int* colR     = (int*)alloc((size_t)EE * 4);
  int* rvR      = (int*)alloc((size_t)EE * 4);
  int* rowcntM  = (int*)alloc((size_t)NN * 4);
  int* rowstM   = (int*)alloc((size_t)NN * 4);
  int* curM     = (int*)alloc((size_t)NN * 4);
  int* colM     = (int*)alloc((size_t)EE * 4);
  float* mvM    = (float*)alloc((size_t)EE * 4);
  int* incl     = (int*)alloc((size_t)NN * 4);
  int* bsum     = (int*)alloc(1024);
  int* boff     = (int*)alloc(1024);
  short* WgT1   = (short*)alloc((size_t)384 * KPW * 2);
  short* WgT2   = (short*)alloc((size_t)384 * KPW * 2);
  short* AT     = (short*)alloc((size_t)1024 * KP * 2);   // 102.8 MB, built once

  short* XT = (short*)TG;   // 384*KP*2 = 38.5 MB fits in TG's 60 MB region

  float* OUT0 = (float*)d_out;
  float* OUT1 = (float*)d_out + (size_t)NN * DD;

  hipMemsetAsync(hs, 0, 3 * 2048, stream);
  hipMemsetAsync(rowcntR, 0, (size_t)NN * 4, stream);
  hipMemsetAsync(rowcntM, 0, (size_t)NN * 4, stream);

  // ---- static prep ----
  k_colsum<<<dim3(196, 2), 512, 0, stream>>>(head, tail, hs, ts);
  k_hist_lds<<<256, 256, RR * 4, stream>>>(rval, EE, RR, cntR);
  k_hist_glob<<<512, 256, 0, stream>>>(ridx, EE, rowcntR);
  k_scan_part<<<196, 256, 0, stream>>>(rowcntR, NN, incl, bsum);
  k_scan_mid<<<1, 1, 0, stream>>>(bsum, 196, boff);
  k_scan_add<<<196, 256, 0, stream>>>(incl, rowcntR, boff, NN, rowstR, curR);
  k_scatter_r<<<512, 256, 0, stream>>>(ridx, ridx + EE, rval, EE, curR, colR, rvR);
  k_hist_glob<<<512, 256, 0, stream>>>(midx, EE, rowcntM);
  k_scan_part<<<196, 256, 0, stream>>>(rowcntM, NN, incl, bsum);
  k_scan_mid<<<1, 1, 0, stream>>>(bsum, 196, boff);
  k_scan_add<<<196, 256, 0, stream>>>(incl, rowcntM, boff, NN, rowstM, curM);
  k_scatter_m<<<512, 256, 0, stream>>>(midx, midx + EE, mval, EE, curM, colM, mvM);
  k_prep_at<<<dim3(784, 16), 256, 0, stream>>>(head, tail, AT);
  k_prep_t<<<dim3(5, 6), 256, 0, stream>>>(Wg1, DD, DD, WgT1, KPW);
  k_prep_t<<<dim3(5, 6), 256, 0, stream>>>(Wg2, DD, DD, WgT2, KPW);

  // ---- round 1 ----
  hipMemsetAsync(acc, 0, 1000 * DD * 4, stream);
  k_prep_t<<<dim3(784, 6), 256, 0, stream>>>(X0, NN, DD, XT, KP);
  k_gemm_cr2<<<dim3(8, 3, 32), 256, 0, stream>>>(AT, XT, acc);
  k_assemble<<<586, 256, 0, stream>>>(acc, hs, ts, dualX);
  k_hgemm<<<dim3(32, 38), 256, 0, stream>>>(dualX, W_s, nullptr, hbuf);
  k_rowdot2<<<125, 256, 0, stream>>>(hbuf, a1_s, b1_s, a2_s, b2_s, f1, f2);
  k_attrow2<<<dim3(63, 2), 320, 0, stream>>>(f1, f2, adj, dualX, dualH1);
  k_rowdot2<<<125, 256, 0, stream>>>(dualH1, w_sp1, b_sp1, nullptr, nullptr, tv, nullptr);
  k_cvec<<<1, 512, 0, stream>>>(tv, cntR, cv);
  k_spmm_r<<<12500, 256, 0, stream>>>(rowstR, rowcntR, colR, rvR, cv, X0, X0, 0.1f, X1GC);

  // ---- round 2 ----
  hipMemsetAsync(acc, 0, 1000 * DD * 4, stream);
  k_prep_t<<<dim3(784, 6), 256, 0, stream>>>(X1GC, NN, DD, XT, KP);
  k_gemm_cr2<<<dim3(8, 3, 32), 256, 0, stream>>>(AT, XT, acc);
  k_assemble<<<586, 256, 0, stream>>>(acc, hs, ts, dualX);
  k_hgemm<<<dim3(32, 38), 256, 0, stream>>>(dualX, W_d, b_d, hbuf);
  k_rowdot2<<<125, 256, 0, stream>>>(hbuf, a1_d, b1_d, a2_d, b2_d, f1, f2);
  k_attrow2<<<dim3(63, 2), 320, 0, stream>>>(f1, f2, adj, dualH1, dualH2);
  k_rowdot2<<<125, 256, 0, stream>>>(dualH2, w_sp2, b_sp2, nullptr, nullptr, tv, nullptr);
  k_cvec<<<1, 512, 0, stream>>>(tv, cntR, cv);
  k_spmm_r<<<12500, 256, 0, stream>>>(rowstR, rowcntR, colR, rvR, cv, X1GC, X0, 0.3f, X2);

  // ---- GCN + highway ----
  k_gate2<<<dim3(391, 3), 256, 0, stream>>>(X2, WgT1, bg1, TG);
  k_spmm_m<<<12500, 256, 0, stream>>>(rowstM, rowcntM, colM, mvM, X2, w0_1, TG, X2, X1GC);
  k_gate2<<<dim3(391, 3), 256, 0, stream>>>(X1GC, WgT2, bg2, TG);
  k_spmm_m<<<12500, 256, 0, stream>>>(rowstM, rowcntM, colM, mvM, X1GC, w0_2, TG, X1GC, OUT0);

  // ---- round 3 (dual only) ----
  hipMemsetAsync(acc, 0, 1000 * DD * 4, stream);
  k_prep_t<<<dim3(784, 6), 256, 0, stream>>>(OUT0, NN, DD, XT, KP);
  k_gemm_cr2<<<dim3(8, 3, 32), 256, 0, stream>>>(AT, XT, acc);
  k_assemble<<<586, 256, 0, stream>>>(acc, hs, ts, dualX);
  k_hgemm<<<dim3(32, 38), 256, 0, stream>>>(dualX, W_d, b_d, hbuf);
  k_rowdot2<<<125, 256, 0, stream>>>(hbuf, a1_d, b1_d, a2_d, b2_d, f1, f2);
  k_attrow2<<<dim3(63, 2), 320, 0, stream>>>(f1, f2, adj, dualH2, OUT1);
}

// Round 9
// 1864.727 us; speedup vs baseline: 1.5753x; 1.0614x over previous
//
#include <hip/hip_runtime.h>
#include <hip/hip_bf16.h>

#define NN 50000
#define RR 500
#define DD 300
#define HH 600
#define EE 500000
#define KP 50176      // 50000 padded to multiple of 32 (32 k-splits x 1568)
#define KPW 320       // 300 padded to multiple of 32 (gate GEMM K)

typedef short bf16x8 __attribute__((ext_vector_type(8)));
typedef float f32x4  __attribute__((ext_vector_type(4)));

__device__ __forceinline__ short f2bf(float f){
  union { float f; unsigned u; } v; v.f = f;
  unsigned r = v.u + 0x7fffu + ((v.u >> 16) & 1u);   // RNE
  return (short)(r >> 16);
}

// ---------------- histograms ----------------
__global__ void k_hist_lds(const int* __restrict__ v, int n, int nb, int* __restrict__ bins){
  extern __shared__ int lb[];
  for (int i = threadIdx.x; i < nb; i += blockDim.x) lb[i] = 0;
  __syncthreads();
  for (int i = blockIdx.x * blockDim.x + threadIdx.x; i < n; i += gridDim.x * blockDim.x)
    atomicAdd(&lb[v[i]], 1);
  __syncthreads();
  for (int i = threadIdx.x; i < nb; i += blockDim.x) if (lb[i]) atomicAdd(&bins[i], lb[i]);
}

__global__ void k_hist_glob(const int* __restrict__ v, int n, int* __restrict__ bins){
  for (int i = blockIdx.x * blockDim.x + threadIdx.x; i < n; i += gridDim.x * blockDim.x)
    atomicAdd(&bins[v[i]], 1);
}

// ---------------- scan (exclusive) ----------------
__global__ void k_scan_part(const int* __restrict__ cnt, int n, int* __restrict__ incl, int* __restrict__ bsum){
  __shared__ int s[256];
  int i = blockIdx.x * 256 + threadIdx.x;
  int v = (i < n) ? cnt[i] : 0;
  s[threadIdx.x] = v; __syncthreads();
  for (int off = 1; off < 256; off <<= 1){
    int t = (threadIdx.x >= off) ? s[threadIdx.x - off] : 0;
    __syncthreads();
    s[threadIdx.x] += t;
    __syncthreads();
  }
  if (i < n) incl[i] = s[threadIdx.x];
  if (threadIdx.x == 255) bsum[blockIdx.x] = s[255];
}

__global__ void k_scan_mid(const int* __restrict__ bsum, int nb, int* __restrict__ boff){
  if (threadIdx.x == 0 && blockIdx.x == 0){
    int run = 0;
    for (int b = 0; b < nb; ++b){ boff[b] = run; run += bsum[b]; }
  }
}

__global__ void k_scan_add(const int* __restrict__ incl, const int* __restrict__ cnt,
                           const int* __restrict__ boff, int n,
                           int* __restrict__ rowst, int* __restrict__ cur){
  int i = blockIdx.x * 256 + threadIdx.x;
  if (i < n){
    int v = incl[i] - cnt[i] + boff[blockIdx.x];
    rowst[i] = v; cur[i] = v;
  }
}

// ---------------- CSR scatter ----------------
__global__ void k_scatter_r(const int* __restrict__ dst, const int* __restrict__ src,
                            const int* __restrict__ rv, int n, int* __restrict__ cur,
                            int* __restrict__ colv, int* __restrict__ rvv){
  for (int i = blockIdx.x * blockDim.x + threadIdx.x; i < n; i += gridDim.x * blockDim.x){
    int p = atomicAdd(&cur[dst[i]], 1);
    colv[p] = src[i]; rvv[p] = rv[i];
  }
}

__global__ void k_scatter_m(const int* __restrict__ dst, const int* __restrict__ src,
                            const float* __restrict__ mv, int n, int* __restrict__ cur,
                            int* __restrict__ colv, float* __restrict__ mvv){
  for (int i = blockIdx.x * blockDim.x + threadIdx.x; i < n; i += gridDim.x * blockDim.x){
    int p = atomicAdd(&cur[dst[i]], 1);
    colv[p] = src[i]; mvv[p] = mv[i];
  }
}

// ---------------- transpose+convert AT + fused colsum ----------------
// AT[m][k] bf16 from head/tail [k][m] f32; also hs[c]=sum_k head[k][c], ts likewise.
// head/tail entries are exactly 0.0/1.0 -> f32 partial sums are exact.
__global__ __launch_bounds__(256) void k_prep_at(const float* __restrict__ head,
                                                 const float* __restrict__ tail,
                                                 short* __restrict__ AT,
                                                 float* __restrict__ hs, float* __restrict__ ts){
  __shared__ short Ls[64][68];
  __shared__ float redf[16][64];
  const int k0 = blockIdx.x * 64, m0 = blockIdx.y * 64;
  const int t = threadIdx.x;
  float p0 = 0.f, p1 = 0.f, p2 = 0.f, p3 = 0.f;
  #pragma unroll
  for (int u = 0; u < 4; ++u){
    int kl = (t >> 4) + 16 * u;
    int ml = (t & 15) * 4;
    int kg = k0 + kl, mg = m0 + ml;
    float4 v = {0.f, 0.f, 0.f, 0.f};
    if (kg < NN && mg < 1000){
      v = (mg < RR) ? *(const float4*)(head + (size_t)kg * RR + mg)
                    : *(const float4*)(tail + (size_t)kg * RR + (mg - RR));
    }
    Ls[kl][ml + 0] = f2bf(v.x);
    Ls[kl][ml + 1] = f2bf(v.y);
    Ls[kl][ml + 2] = f2bf(v.z);
    Ls[kl][ml + 3] = f2bf(v.w);
    p0 += v.x; p1 += v.y; p2 += v.z; p3 += v.w;
  }
  {
    int j = t >> 4, c = (t & 15) * 4;
    redf[j][c + 0] = p0;
    redf[j][c + 1] = p1;
    redf[j][c + 2] = p2;
    redf[j][c + 3] = p3;
  }
  __syncthreads();
  #pragma unroll
  for (int u = 0; u < 4; ++u){
    int m = (t >> 4) + 16 * u;
    int kq = (t & 15) * 4;
    short4 w = make_short4(Ls[kq][m], Ls[kq + 1][m], Ls[kq + 2][m], Ls[kq + 3][m]);
    *(short4*)(AT + (size_t)(m0 + m) * KP + k0 + kq) = w;
  }
  if (t < 64){
    float s = 0.f;
    #pragma unroll
    for (int j = 0; j < 16; ++j) s += redf[j][t];
    int c = m0 + t;
    if (c < RR) atomicAdd(&hs[c], s);
    else if (c < 1000) atomicAdd(&ts[c - RR], s);
  }
}

// ---------------- generic transpose+convert f32[k][m] -> bf16[m_pad][KPo] ----------------
__global__ __launch_bounds__(256) void k_prep_t(const float* __restrict__ src, int Krows, int Mcols,
                                                short* __restrict__ dst, int KPo){
  __shared__ short Ls[64][68];
  const int k0 = blockIdx.x * 64, m0 = blockIdx.y * 64;
  const int t = threadIdx.x;
  #pragma unroll
  for (int u = 0; u < 4; ++u){
    int kl = (t >> 4) + 16 * u;
    int ml = (t & 15) * 4;
    int kg = k0 + kl, mg = m0 + ml;
    float4 v = {0.f, 0.f, 0.f, 0.f};
    if (kg < Krows && mg < Mcols) v = *(const float4*)(src + (size_t)kg * Mcols + mg);
    Ls[kl][ml + 0] = f2bf(v.x);
    Ls[kl][ml + 1] = f2bf(v.y);
    Ls[kl][ml + 2] = f2bf(v.z);
    Ls[kl][ml + 3] = f2bf(v.w);
  }
  __syncthreads();
  #pragma unroll
  for (int u = 0; u < 4; ++u){
    int m = (t >> 4) + 16 * u;
    int kq = (t & 15) * 4;
    short4 w = make_short4(Ls[kq][m], Ls[kq + 1][m], Ls[kq + 2][m], Ls[kq + 3][m]);
    *(short4*)(dst + (size_t)(m0 + m) * KPo + k0 + kq) = w;
  }
}

// ---------------- compute_r GEMM v2: both operands pre-transposed bf16 [spatial][k] ----------
__global__ __launch_bounds__(256) void k_gemm_cr2(
    const short* __restrict__ AT, const short* __restrict__ XT, float* __restrict__ acc)
{
  const int m0 = blockIdx.x * 128;
  const int n0 = blockIdx.y * 128;
  const int k0 = blockIdx.z * 1568;

  __shared__ short As[128 * 32];
  __shared__ short Bs[128 * 32];
  const int tid = threadIdx.x;
  const int lane = tid & 63, wave = tid >> 6;
  const int wr = wave >> 1, wc = wave & 1;

  const int r0 = tid >> 2;
  const int slot = tid & 3;
  const size_t agA = (size_t)(m0 + r0) * KP + slot * 8;
  const size_t agB = (size_t)(m0 + r0 + 64) * KP + slot * 8;
  const size_t bgA = (size_t)(n0 + r0) * KP + slot * 8;
  const size_t bgB = (size_t)(n0 + r0 + 64) * KP + slot * 8;
  short* alA = As + r0 * 32 + slot * 8;
  short* alB = As + (r0 + 64) * 32 + slot * 8;
  short* blA = Bs + r0 * 32 + slot * 8;
  short* blB = Bs + (r0 + 64) * 32 + slot * 8;

  f32x4 c[4][4];
  #pragma unroll
  for (int i = 0; i < 4; ++i)
    #pragma unroll
    for (int j = 0; j < 4; ++j)
      #pragma unroll
      for (int q = 0; q < 4; ++q) c[i][j][q] = 0.f;

  const int krow = (lane >> 4) * 8;
  const int rsel = lane & 15;

  for (int kk = k0; kk < k0 + 1568; kk += 32){
    bf16x8 va0 = *(const bf16x8*)(AT + agA + kk);
    bf16x8 va1 = *(const bf16x8*)(AT + agB + kk);
    bf16x8 vb0 = *(const bf16x8*)(XT + bgA + kk);
    bf16x8 vb1 = *(const bf16x8*)(XT + bgB + kk);
    *(bf16x8*)alA = va0;
    *(bf16x8*)alB = va1;
    *(bf16x8*)blA = vb0;
    *(bf16x8*)blB = vb1;
    __syncthreads();
    bf16x8 af[4], bfr[4];
    #pragma unroll
    for (int i = 0; i < 4; ++i){
      af[i]  = *(const bf16x8*)(As + (wr * 64 + i * 16 + rsel) * 32 + krow);
      bfr[i] = *(const bf16x8*)(Bs + (wc * 64 + i * 16 + rsel) * 32 + krow);
    }
    #pragma unroll
    for (int i = 0; i < 4; ++i)
      #pragma unroll
      for (int j = 0; j < 4; ++j)
        c[i][j] = __builtin_amdgcn_mfma_f32_16x16x32_bf16(af[i], bfr[j], c[i][j], 0, 0, 0);
    __syncthreads();
  }
  const int col = lane & 15;
  const int rw0 = (lane >> 4) * 4;
  #pragma unroll
  for (int j = 0; j < 4; ++j){
    int dg = n0 + wc * 64 + j * 16 + col;
    if (dg >= DD) continue;
    #pragma unroll
    for (int i = 0; i < 4; ++i){
      int mg = m0 + wr * 64 + i * 16 + rw0;
      #pragma unroll
      for (int q = 0; q < 4; ++q)
        if (mg + q < 1000) atomicAdd(acc + (mg + q) * DD + dg, c[i][j][q]);
    }
  }
}

// ---------------- assemble dual_X from acc ----------------
__global__ void k_assemble(const float* __restrict__ acc, const float* __restrict__ hs,
                           const float* __restrict__ ts, float* __restrict__ dualX){
  int i = blockIdx.x * 256 + threadIdx.x;
  if (i < RR * DD){
    int r = i / DD, d = i - r * DD;
    dualX[r * HH + d]      = acc[r * DD + d]          / (hs[r] + 1e-9f);
    dualX[r * HH + DD + d] = acc[(RR + r) * DD + d]   / (ts[r] + 1e-9f);
  }
}

// ---------------- h = feat @ W.T + bias  (f32, [500,600]x[600,600]^T) ----------------
__global__ __launch_bounds__(256) void k_hgemm(const float* __restrict__ feat, const float* __restrict__ W,
                                               const float* __restrict__ bias, float* __restrict__ h){
  __shared__ float Fs[16][17], Ws[16][17];
  int tx = threadIdx.x & 15, ty = threadIdx.x >> 4;
  int r0 = blockIdx.x * 16, j0 = blockIdx.y * 16;
  float acc = 0.f;
  for (int k0 = 0; k0 < HH; k0 += 16){
    int k = k0 + tx;
    Fs[ty][tx] = (r0 + ty < RR && k < HH) ? feat[(r0 + ty) * HH + k] : 0.f;
    Ws[ty][tx] = (j0 + ty < HH && k < HH) ? W[(j0 + ty) * HH + k] : 0.f;
    __syncthreads();
    #pragma unroll
    for (int kk = 0; kk < 16; ++kk) acc += Fs[ty][kk] * Ws[tx][kk];
    __syncthreads();
  }
  int rr = r0 + ty, jj = j0 + tx;
  if (rr < RR && jj < HH) h[rr * HH + jj] = acc + (bias ? bias[jj] : 0.f);
}

// ---------------- per-row dots: f1[r]=h[r]·a1+b1, f2[r]=h[r]·a2+b2 ----------------
__global__ void k_rowdot2(const float* __restrict__ Hm, const float* __restrict__ a1, const float* __restrict__ b1,
                          const float* __restrict__ a2, const float* __restrict__ b2,
                          float* __restrict__ f1, float* __restrict__ f2){
  int wave = threadIdx.x >> 6, lane = threadIdx.x & 63;
  int r = blockIdx.x * 4 + wave;
  if (r >= RR) return;
  float s1 = 0.f, s2 = 0.f;
  for (int k = lane; k < HH; k += 64){
    float hv = Hm[r * HH + k];
    s1 += hv * a1[k];
    if (a2) s2 += hv * a2[k];
  }
  #pragma unroll
  for (int off = 32; off; off >>= 1){
    s1 += __shfl_down(s1, off);
    s2 += __shfl_down(s2, off);
  }
  if (lane == 0){
    f1[r] = s1 + b1[0];
    if (f2) f2[r] = s2 + (b2 ? b2[0] : 0.f);
  }
}

// ---------------- fused dense attention, 8 rows/block, val-load amortized ----------------
__global__ __launch_bounds__(320) void k_attrow2(const float* __restrict__ f1, const float* __restrict__ f2,
    const float* __restrict__ adj, const float* __restrict__ val, float* __restrict__ outp){
  __shared__ float coef[8][504];
  const int r0 = blockIdx.x * 8;
  const int t = threadIdx.x;
  const int wave = t >> 6, lane = t & 63;

  if (wave < 4){
    #pragma unroll
    for (int sub = 0; sub < 2; ++sub){
      const int slot = wave * 2 + sub;
      const int r = r0 + slot;
      if (r < RR){
        const float f1r = f1[r];
        float lg[8];
        float mx = -3.0e38f;
        #pragma unroll
        for (int cI = 0; cI < 8; ++cI){
          int j = lane + 64 * cI;
          float l = -3.0e38f;
          if (j < RR){
            l = f1r + f2[j];
            l = (l > 0.f) ? l : 0.01f * l;
            if (adj[r * RR + j] <= 0.f) l -= 1e9f;
          }
          lg[cI] = l;
          mx = fmaxf(mx, l);
        }
        #pragma unroll
        for (int off = 32; off; off >>= 1) mx = fmaxf(mx, __shfl_xor(mx, off));
        float sum = 0.f;
        float ev[8];
        #pragma unroll
        for (int cI = 0; cI < 8; ++cI){
          int j = lane + 64 * cI;
          float e = (j < RR) ? expf(lg[cI] - mx) : 0.f;
          ev[cI] = e;
          sum += e;
        }
        #pragma unroll
        for (int off = 32; off; off >>= 1) sum += __shfl_xor(sum, off);
        float inv = 1.f / sum;
        #pragma unroll
        for (int cI = 0; cI < 8; ++cI){
          int j = lane + 64 * cI;
          if (j < RR) coef[slot][j] = ev[cI] * inv;
        }
      } else {
        #pragma unroll
        for (int cI = 0; cI < 8; ++cI){
          int j = lane + 64 * cI;
          if (j < RR) coef[slot][j] = 0.f;
        }
      }
    }
  }
  __syncthreads();

  if (t < 300){
    const int col = blockIdx.y * 300 + t;
    float acc[8];
    #pragma unroll
    for (int rI = 0; rI < 8; ++rI) acc[rI] = 0.f;
    for (int j = 0; j < RR; j += 4){
      float v0 = val[(j + 0) * HH + col];
      float v1 = val[(j + 1) * HH + col];
      float v2 = val[(j + 2) * HH + col];
      float v3 = val[(j + 3) * HH + col];
      #pragma unroll
      for (int rI = 0; rI < 8; ++rI){
        f32x4 cf = *(const f32x4*)&coef[rI][j];
        acc[rI] += cf[0] * v0 + cf[1] * v1 + cf[2] * v2 + cf[3] * v3;
      }
    }
    #pragma unroll
    for (int rI = 0; rI < 8; ++rI){
      int r = r0 + rI;
      if (r < RR) outp[r * HH + col] = fmaxf(acc[rI], 0.f);
    }
  }
}

// ---------------- global-softmax coefficients per relation ----------------
__global__ void k_cvec(const float* __restrict__ tv, const int* __restrict__ cnt, float* __restrict__ cvec){
  __shared__ float red[512];
  int t = threadIdx.x;
  float lr = -3.0e38f, tval = 0.f;
  if (t < RR){
    tval = tv[t];
    tval = (tval > 0.f) ? tval : 0.01f * tval;
    if (cnt[t] > 0) lr = tval;
  }
  red[t] = lr; __syncthreads();
  for (int off = 256; off; off >>= 1){ if (t < off) red[t] = fmaxf(red[t], red[t + off]); __syncthreads(); }
  float mx = red[0]; __syncthreads();
  float ex = (t < RR) ? expf(tval - mx) : 0.f;
  red[t] = (t < RR) ? ex * (float)cnt[t] : 0.f; __syncthreads();
  for (int off = 256; off; off >>= 1){ if (t < off) red[t] += red[t + off]; __syncthreads(); }
  float inv = 1.f / red[0];
  if (t < RR) cvec[t] = ex * inv;
}

// ---------------- sparse att SpMM: out = base + scale*relu(sum c[rv]*X[src]) ----------------
__global__ __launch_bounds__(256) void k_spmm_r(const int* __restrict__ rowst, const int* __restrict__ rowcnt,
    const int* __restrict__ colv, const int* __restrict__ rvv, const float* __restrict__ cvec,
    const float* __restrict__ Xg, const float* __restrict__ base, float scale, float* __restrict__ outp){
  int wave = threadIdx.x >> 6, lane = threadIdx.x & 63;
  int row = blockIdx.x * 4 + wave;
  if (row >= NN) return;
  int st = rowst[row], cn = rowcnt[row];
  float a0 = 0.f, a1 = 0.f, a2 = 0.f, a3 = 0.f, a4 = 0.f;
  for (int e = 0; e < cn; ++e){
    int s = colv[st + e];
    float w = cvec[rvv[st + e]];
    const float* xr = Xg + (size_t)s * DD;
    a0 += w * xr[lane];
    a1 += w * xr[lane + 64];
    a2 += w * xr[lane + 128];
    a3 += w * xr[lane + 192];
    if (lane < 44) a4 += w * xr[lane + 256];
  }
  size_t ro = (size_t)row * DD;
  outp[ro + lane]       = base[ro + lane]       + scale * fmaxf(a0, 0.f);
  outp[ro + lane + 64]  = base[ro + lane + 64]  + scale * fmaxf(a1, 0.f);
  outp[ro + lane + 128] = base[ro + lane + 128] + scale * fmaxf(a2, 0.f);
  outp[ro + lane + 192] = base[ro + lane + 192] + scale * fmaxf(a3, 0.f);
  if (lane < 44) outp[ro + lane + 256] = base[ro + lane + 256] + scale * fmaxf(a4, 0.f);
}

// ---------------- diag-GCN SpMM + highway blend ----------------
__global__ __launch_bounds__(256) void k_spmm_m(const int* __restrict__ rowst, const int* __restrict__ rowcnt,
    const int* __restrict__ colv, const float* __restrict__ mvv,
    const float* __restrict__ Xg, const float* __restrict__ w0, const float* __restrict__ tg,
    const float* __restrict__ base, float* __restrict__ outp){
  int wave = threadIdx.x >> 6, lane = threadIdx.x & 63;
  int row = blockIdx.x * 4 + wave;
  if (row >= NN) return;
  int st = rowst[row], cn = rowcnt[row];
  float a0 = 0.f, a1 = 0.f, a2 = 0.f, a3 = 0.f, a4 = 0.f;
  for (int e = 0; e < cn; ++e){
    int s = colv[st + e];
    float w = mvv[st + e];
    const float* xr = Xg + (size_t)s * DD;
    a0 += w * xr[lane];
    a1 += w * xr[lane + 64];
    a2 += w * xr[lane + 128];
    a3 += w * xr[lane + 192];
    if (lane < 44) a4 += w * xr[lane + 256];
  }
  size_t ro = (size_t)row * DD;
  #pragma unroll
  for (int u = 0; u < 5; ++u){
    int d = lane + u * 64;
    if (d < DD){
      float acc = (u == 0) ? a0 : (u == 1) ? a1 : (u == 2) ? a2 : (u == 3) ? a3 : a4;
      float g = fmaxf(w0[d] * acc, 0.f);
      float tvv = tg[ro + d];
      outp[ro + d] = tvv * g + (1.f - tvv) * base[ro + d];
    }
  }
}

// ---------------- highway gate GEMM v2: Tg = sigmoid(Xin @ Wg + bg) with WgT bf16 ----------
__global__ __launch_bounds__(256) void k_gate2(const float* __restrict__ Xin,
                                               const short* __restrict__ WgT,
                                               const float* __restrict__ bg, float* __restrict__ Tg){
  const int m0 = blockIdx.x * 128, n0 = blockIdx.y * 128;
  __shared__ short As[128 * 32];
  __shared__ short Bs[128 * 32];
  const int tid = threadIdx.x;
  const int lane = tid & 63, wave = tid >> 6;
  const int wr = wave >> 1, wc = wave & 1;

  const int r0 = tid >> 2;
  const int slot = tid & 3;
  const size_t bgA = (size_t)(n0 + r0) * KPW + slot * 8;
  const size_t bgB = (size_t)(n0 + r0 + 64) * KPW + slot * 8;
  short* blA = Bs + r0 * 32 + slot * 8;
  short* blB = Bs + (r0 + 64) * 32 + slot * 8;

  f32x4 c[4][4];
  #pragma unroll
  for (int i = 0; i < 4; ++i)
    #pragma unroll
    for (int j = 0; j < 4; ++j)
      #pragma unroll
      for (int q = 0; q < 4; ++q) c[i][j][q] = 0.f;

  const int krow = (lane >> 4) * 8;
  const int rsel = lane & 15;

  for (int kk = 0; kk < KPW; kk += 32){
    #pragma unroll
    for (int u = 0; u < 4; ++u){
      int f4 = tid + u * 256;
      int ml = f4 >> 3;
      int kl = (f4 & 7) * 4;
      int mg = m0 + ml, kg = kk + kl;
      float4 v = {0.f, 0.f, 0.f, 0.f};
      if (mg < NN && kg < DD) v = *(const float4*)(Xin + (size_t)mg * DD + kg);
      ushort4 w = make_ushort4((unsigned short)f2bf(v.x), (unsigned short)f2bf(v.y),
                               (unsigned short)f2bf(v.z), (unsigned short)f2bf(v.w));
      *reinterpret_cast<ushort4*>(&As[ml * 32 + kl]) = w;
    }
    *(bf16x8*)blA = *(const bf16x8*)(WgT + bgA + kk);
    *(bf16x8*)blB = *(const bf16x8*)(WgT + bgB + kk);
    __syncthreads();
    bf16x8 af[4], bfr[4];
    #pragma unroll
    for (int i = 0; i < 4; ++i){
      af[i]  = *(const bf16x8*)(As + (wr * 64 + i * 16 + rsel) * 32 + krow);
      bfr[i] = *(const bf16x8*)(Bs + (wc * 64 + i * 16 + rsel) * 32 + krow);
    }
    #pragma unroll
    for (int i = 0; i < 4; ++i)
      #pragma unroll
      for (int j = 0; j < 4; ++j)
        c[i][j] = __builtin_amdgcn_mfma_f32_16x16x32_bf16(af[i], bfr[j], c[i][j], 0, 0, 0);
    __syncthreads();
  }
  const int col = lane & 15;
  const int rw0 = (lane >> 4) * 4;
  #pragma unroll
  for (int j = 0; j < 4; ++j){
    int ng = n0 + wc * 64 + j * 16 + col;
    if (ng >= DD) continue;
    float bias = bg[ng];
    #pragma unroll
    for (int i = 0; i < 4; ++i){
      int mg = m0 + wr * 64 + i * 16 + rw0;
      #pragma unroll
      for (int q = 0; q < 4; ++q){
        if (mg + q < NN){
          float x = c[i][j][q] + bias;
          Tg[(size_t)(mg + q) * DD + ng] = 1.f / (1.f + expf(-x));
        }
      }
    }
  }
}

// ================= host =================
extern "C" void kernel_launch(void* const* d_in, const int* in_sizes, int n_in,
                              void* d_out, int out_size, void* d_ws, size_t ws_size,
                              hipStream_t stream)
{
  (void)in_sizes; (void)n_in; (void)out_size; (void)ws_size;
  const float* X0   = (const float*)d_in[0];
  const float* head = (const float*)d_in[1];
  const float* tail = (const float*)d_in[2];
  const float* adj  = (const float*)d_in[3];
  const int*   ridx = (const int*)d_in[4];
  const int*   rval = (const int*)d_in[5];
  const int*   midx = (const int*)d_in[6];
  const float* mval = (const float*)d_in[7];
  const float* W_s  = (const float*)d_in[8];
  const float* a1_s = (const float*)d_in[9];
  const float* b1_s = (const float*)d_in[10];
  const float* a2_s = (const float*)d_in[11];
  const float* b2_s = (const float*)d_in[12];
  const float* w_sp1= (const float*)d_in[13];
  const float* b_sp1= (const float*)d_in[14];
  const float* w_sp2= (const float*)d_in[15];
  const float* b_sp2= (const float*)d_in[16];
  const float* W_d  = (const float*)d_in[17];
  const float* b_d  = (const float*)d_in[18];
  const float* a1_d = (const float*)d_in[19];
  const float* b1_d = (const float*)d_in[20];
  const float* a2_d = (const float*)d_in[21];
  const float* b2_d = (const float*)d_in[22];
  const float* w0_1 = (const float*)d_in[23];
  const float* w0_2 = (const float*)d_in[24];
  const float* Wg1  = (const float*)d_in[25];
  const float* bg1  = (const float*)d_in[26];
  const float* Wg2  = (const float*)d_in[27];
  const float* bg2  = (const float*)d_in[28];

  char* ws = (char*)d_ws;
  size_t off = 0;
  auto alloc = [&](size_t bytes)->char*{
    char* p = ws + off;
    off += (bytes + 255) & ~(size_t)255;
    return p;
  };
  float* acc    = (float*)alloc(1000 * DD * 4);
  float* X1GC   = (float*)alloc((size_t)NN * DD * 4);
  float* X2     = (float*)alloc((size_t)NN * DD * 4);
  float* TG     = (float*)alloc((size_t)NN * DD * 4);   // aliased with XT (lifetimes disjoint)
  float* dualX  = (float*)alloc(RR * HH * 4);
  float* dualH1 = (float*)alloc(RR * HH * 4);
  float* dualH2 = (float*)alloc(RR * HH * 4);
  float* hbuf   = (float*)alloc(RR * HH * 4);
  float* hs     = (float*)alloc(2048);
  float* ts     = (float*)alloc(2048);
  int*   cntR   = (int*)alloc(2048);
  float* f1     = (float*)alloc(2048);
  float* f2     = (float*)alloc(2048);
  float* tv     = (float*)alloc(2048);
  float* cv     = (float*)alloc(2048);
  int* rowcntR  = (int*)alloc((size_t)NN * 4);
  int* rowstR   = (int*)alloc((size_t)NN * 4);
  int* curR     = (int*)alloc((size_t)NN * 4);
  int* colR     = (int*)alloc((size_t)EE * 4);
  int* rvR      = (int*)alloc((size_t)EE * 4);
  int* rowcntM  = (int*)alloc((size_t)NN * 4);
  int* rowstM   = (int*)alloc((size_t)NN * 4);
  int* curM     = (int*)alloc((size_t)NN * 4);
  int* colM     = (int*)alloc((size_t)EE * 4);
  float* mvM    = (float*)alloc((size_t)EE * 4);
  int* incl     = (int*)alloc((size_t)NN * 4);
  int* bsum     = (int*)alloc(1024);
  int* boff     = (int*)alloc(1024);
  short* WgT1   = (short*)alloc((size_t)384 * KPW * 2);
  short* WgT2   = (short*)alloc((size_t)384 * KPW * 2);
  short* AT     = (short*)alloc((size_t)1024 * KP * 2);   // 102.8 MB, built once

  short* XT = (short*)TG;   // 384*KP*2 = 38.5 MB fits in TG's 60 MB region

  float* OUT0 = (float*)d_out;
  float* OUT1 = (float*)d_out + (size_t)NN * DD;

  hipMemsetAsync(hs, 0, 3 * 2048, stream);
  hipMemsetAsync(rowcntR, 0, (size_t)NN * 4, stream);
  hipMemsetAsync(rowcntM, 0, (size_t)NN * 4, stream);

  // ---- static prep ----
  k_hist_lds<<<256, 256, RR * 4, stream>>>(rval, EE, RR, cntR);
  k_hist_glob<<<512, 256, 0, stream>>>(ridx, EE, rowcntR);
  k_scan_part<<<196, 256, 0, stream>>>(rowcntR, NN, incl, bsum);
  k_scan_mid<<<1, 1, 0, stream>>>(bsum, 196, boff);
  k_scan_add<<<196, 256, 0, stream>>>(incl, rowcntR, boff, NN, rowstR, curR);
  k_scatter_r<<<512, 256, 0, stream>>>(ridx, ridx + EE, rval, EE, curR, colR, rvR);
  k_hist_glob<<<512, 256, 0, stream>>>(midx, EE, rowcntM);
  k_scan_part<<<196, 256, 0, stream>>>(rowcntM, NN, incl, bsum);
  k_scan_mid<<<1, 1, 0, stream>>>(bsum, 196, boff);
  k_scan_add<<<196, 256, 0, stream>>>(incl, rowcntM, boff, NN, rowstM, curM);
  k_scatter_m<<<512, 256, 0, stream>>>(midx, midx + EE, mval, EE, curM, colM, mvM);
  k_prep_at<<<dim3(784, 16), 256, 0, stream>>>(head, tail, AT, hs, ts);
  k_prep_t<<<dim3(5, 6), 256, 0, stream>>>(Wg1, DD, DD, WgT1, KPW);
  k_prep_t<<<dim3(5, 6), 256, 0, stream>>>(Wg2, DD, DD, WgT2, KPW);

  // ---- round 1 ----
  hipMemsetAsync(acc, 0, 1000 * DD * 4, stream);
  k_prep_t<<<dim3(784, 6), 256, 0, stream>>>(X0, NN, DD, XT, KP);
  k_gemm_cr2<<<dim3(8, 3, 32), 256, 0, stream>>>(AT, XT, acc);
  k_assemble<<<586, 256, 0, stream>>>(acc, hs, ts, dualX);
  k_hgemm<<<dim3(32, 38), 256, 0, stream>>>(dualX, W_s, nullptr, hbuf);
  k_rowdot2<<<125, 256, 0, stream>>>(hbuf, a1_s, b1_s, a2_s, b2_s, f1, f2);
  k_attrow2<<<dim3(63, 2), 320, 0, stream>>>(f1, f2, adj, dualX, dualH1);
  k_rowdot2<<<125, 256, 0, stream>>>(dualH1, w_sp1, b_sp1, nullptr, nullptr, tv, nullptr);
  k_cvec<<<1, 512, 0, stream>>>(tv, cntR, cv);
  k_spmm_r<<<12500, 256, 0, stream>>>(rowstR, rowcntR, colR, rvR, cv, X0, X0, 0.1f, X1GC);

  // ---- round 2 ----
  hipMemsetAsync(acc, 0, 1000 * DD * 4, stream);
  k_prep_t<<<dim3(784, 6), 256, 0, stream>>>(X1GC, NN, DD, XT, KP);
  k_gemm_cr2<<<dim3(8, 3, 32), 256, 0, stream>>>(AT, XT, acc);
  k_assemble<<<586, 256, 0, stream>>>(acc, hs, ts, dualX);
  k_hgemm<<<dim3(32, 38), 256, 0, stream>>>(dualX, W_d, b_d, hbuf);
  k_rowdot2<<<125, 256, 0, stream>>>(hbuf, a1_d, b1_d, a2_d, b2_d, f1, f2);
  k_attrow2<<<dim3(63, 2), 320, 0, stream>>>(f1, f2, adj, dualH1, dualH2);
  k_rowdot2<<<125, 256, 0, stream>>>(dualH2, w_sp2, b_sp2, nullptr, nullptr, tv, nullptr);
  k_cvec<<<1, 512, 0, stream>>>(tv, cntR, cv);
  k_spmm_r<<<12500, 256, 0, stream>>>(rowstR, rowcntR, colR, rvR, cv, X1GC, X0, 0.3f, X2);

  // ---- GCN + highway ----
  k_gate2<<<dim3(391, 3), 256, 0, stream>>>(X2, WgT1, bg1, TG);
  k_spmm_m<<<12500, 256, 0, stream>>>(rowstM, rowcntM, colM, mvM, X2, w0_1, TG, X2, X1GC);
  k_gate2<<<dim3(391, 3), 256, 0, stream>>>(X1GC, WgT2, bg2, TG);
  k_spmm_m<<<12500, 256, 0, stream>>>(rowstM, rowcntM, colM, mvM, X1GC, w0_2, TG, X1GC, OUT0);

  // ---- round 3 (dual only) ----
  hipMemsetAsync(acc, 0, 1000 * DD * 4, stream);
  k_prep_t<<<dim3(784, 6), 256, 0, stream>>>(OUT0, NN, DD, XT, KP);
  k_gemm_cr2<<<dim3(8, 3, 32), 256, 0, stream>>>(AT, XT, acc);
  k_assemble<<<586, 256, 0, stream>>>(acc, hs, ts, dualX);
  k_hgemm<<<dim3(32, 38), 256, 0, stream>>>(dualX, W_d, b_d, hbuf);
  k_rowdot2<<<125, 256, 0, stream>>>(hbuf, a1_d, b1_d, a2_d, b2_d, f1, f2);
  k_attrow2<<<dim3(63, 2), 320, 0, stream>>>(f1, f2, adj, dualH2, OUT1);
}

// Round 11
// 1850.154 us; speedup vs baseline: 1.5877x; 1.0079x over previous
//
#include <hip/hip_runtime.h>
#include <hip/hip_bf16.h>

#define NN 50000
#define RR 500
#define DD 300
#define HH 600
#define EE 500000
#define KP 50176      // 50000 padded to multiple of 32 (32 k-splits x 1568)
#define KPW 320       // 300 padded to multiple of 32 (gate GEMM K)

typedef short bf16x8 __attribute__((ext_vector_type(8)));
typedef float f32x4  __attribute__((ext_vector_type(4)));

typedef __attribute__((address_space(1))) const void gas_void;
typedef __attribute__((address_space(3))) void las_void;

__device__ __forceinline__ short f2bf(float f){
  union { float f; unsigned u; } v; v.f = f;
  unsigned r = v.u + 0x7fffu + ((v.u >> 16) & 1u);   // RNE
  return (short)(r >> 16);
}

// ---------------- histograms ----------------
__global__ void k_hist_lds(const int* __restrict__ v, int n, int nb, int* __restrict__ bins){
  extern __shared__ int lb[];
  for (int i = threadIdx.x; i < nb; i += blockDim.x) lb[i] = 0;
  __syncthreads();
  for (int i = blockIdx.x * blockDim.x + threadIdx.x; i < n; i += gridDim.x * blockDim.x)
    atomicAdd(&lb[v[i]], 1);
  __syncthreads();
  for (int i = threadIdx.x; i < nb; i += blockDim.x) if (lb[i]) atomicAdd(&bins[i], lb[i]);
}

__global__ void k_hist_glob(const int* __restrict__ v, int n, int* __restrict__ bins){
  for (int i = blockIdx.x * blockDim.x + threadIdx.x; i < n; i += gridDim.x * blockDim.x)
    atomicAdd(&bins[v[i]], 1);
}

// ---------------- scan (exclusive) ----------------
__global__ void k_scan_part(const int* __restrict__ cnt, int n, int* __restrict__ incl, int* __restrict__ bsum){
  __shared__ int s[256];
  int i = blockIdx.x * 256 + threadIdx.x;
  int v = (i < n) ? cnt[i] : 0;
  s[threadIdx.x] = v; __syncthreads();
  for (int off = 1; off < 256; off <<= 1){
    int t = (threadIdx.x >= off) ? s[threadIdx.x - off] : 0;
    __syncthreads();
    s[threadIdx.x] += t;
    __syncthreads();
  }
  if (i < n) incl[i] = s[threadIdx.x];
  if (threadIdx.x == 255) bsum[blockIdx.x] = s[255];
}

__global__ void k_scan_mid(const int* __restrict__ bsum, int nb, int* __restrict__ boff){
  if (threadIdx.x == 0 && blockIdx.x == 0){
    int run = 0;
    for (int b = 0; b < nb; ++b){ boff[b] = run; run += bsum[b]; }
  }
}

__global__ void k_scan_add(const int* __restrict__ incl, const int* __restrict__ cnt,
                           const int* __restrict__ boff, int n,
                           int* __restrict__ rowst, int* __restrict__ cur){
  int i = blockIdx.x * 256 + threadIdx.x;
  if (i < n){
    int v = incl[i] - cnt[i] + boff[blockIdx.x];
    rowst[i] = v; cur[i] = v;
  }
}

// ---------------- CSR scatter ----------------
__global__ void k_scatter_r(const int* __restrict__ dst, const int* __restrict__ src,
                            const int* __restrict__ rv, int n, int* __restrict__ cur,
                            int* __restrict__ colv, int* __restrict__ rvv){
  for (int i = blockIdx.x * blockDim.x + threadIdx.x; i < n; i += gridDim.x * blockDim.x){
    int p = atomicAdd(&cur[dst[i]], 1);
    colv[p] = src[i]; rvv[p] = rv[i];
  }
}

__global__ void k_scatter_m(const int* __restrict__ dst, const int* __restrict__ src,
                            const float* __restrict__ mv, int n, int* __restrict__ cur,
                            int* __restrict__ colv, float* __restrict__ mvv){
  for (int i = blockIdx.x * blockDim.x + threadIdx.x; i < n; i += gridDim.x * blockDim.x){
    int p = atomicAdd(&cur[dst[i]], 1);
    colv[p] = src[i]; mvv[p] = mv[i];
  }
}

// ---------------- transpose+convert AT + fused colsum ----------------
__global__ __launch_bounds__(256) void k_prep_at(const float* __restrict__ head,
                                                 const float* __restrict__ tail,
                                                 short* __restrict__ AT,
                                                 float* __restrict__ hs, float* __restrict__ ts){
  __shared__ short Ls[64][68];
  __shared__ float redf[16][64];
  const int k0 = blockIdx.x * 64, m0 = blockIdx.y * 64;
  const int t = threadIdx.x;
  float p0 = 0.f, p1 = 0.f, p2 = 0.f, p3 = 0.f;
  #pragma unroll
  for (int u = 0; u < 4; ++u){
    int kl = (t >> 4) + 16 * u;
    int ml = (t & 15) * 4;
    int kg = k0 + kl, mg = m0 + ml;
    float4 v = {0.f, 0.f, 0.f, 0.f};
    if (kg < NN && mg < 1000){
      v = (mg < RR) ? *(const float4*)(head + (size_t)kg * RR + mg)
                    : *(const float4*)(tail + (size_t)kg * RR + (mg - RR));
    }
    Ls[kl][ml + 0] = f2bf(v.x);
    Ls[kl][ml + 1] = f2bf(v.y);
    Ls[kl][ml + 2] = f2bf(v.z);
    Ls[kl][ml + 3] = f2bf(v.w);
    p0 += v.x; p1 += v.y; p2 += v.z; p3 += v.w;
  }
  {
    int j = t >> 4, c = (t & 15) * 4;
    redf[j][c + 0] = p0;
    redf[j][c + 1] = p1;
    redf[j][c + 2] = p2;
    redf[j][c + 3] = p3;
  }
  __syncthreads();
  #pragma unroll
  for (int u = 0; u < 4; ++u){
    int m = (t >> 4) + 16 * u;
    int kq = (t & 15) * 4;
    short4 w = make_short4(Ls[kq][m], Ls[kq + 1][m], Ls[kq + 2][m], Ls[kq + 3][m]);
    *(short4*)(AT + (size_t)(m0 + m) * KP + k0 + kq) = w;
  }
  if (t < 64){
    float s = 0.f;
    #pragma unroll
    for (int j = 0; j < 16; ++j) s += redf[j][t];
    int c = m0 + t;
    if (c < RR) atomicAdd(&hs[c], s);
    else if (c < 1000) atomicAdd(&ts[c - RR], s);
  }
}

// ---------------- generic transpose+convert f32[k][m] -> bf16[m_pad][KPo] ----------------
__global__ __launch_bounds__(256) void k_prep_t(const float* __restrict__ src, int Krows, int Mcols,
                                                short* __restrict__ dst, int KPo){
  __shared__ short Ls[64][68];
  const int k0 = blockIdx.x * 64, m0 = blockIdx.y * 64;
  const int t = threadIdx.x;
  #pragma unroll
  for (int u = 0; u < 4; ++u){
    int kl = (t >> 4) + 16 * u;
    int ml = (t & 15) * 4;
    int kg = k0 + kl, mg = m0 + ml;
    float4 v = {0.f, 0.f, 0.f, 0.f};
    if (kg < Krows && mg < Mcols) v = *(const float4*)(src + (size_t)kg * Mcols + mg);
    Ls[kl][ml + 0] = f2bf(v.x);
    Ls[kl][ml + 1] = f2bf(v.y);
    Ls[kl][ml + 2] = f2bf(v.z);
    Ls[kl][ml + 3] = f2bf(v.w);
  }
  __syncthreads();
  #pragma unroll
  for (int u = 0; u < 4; ++u){
    int m = (t >> 4) + 16 * u;
    int kq = (t & 15) * 4;
    short4 w = make_short4(Ls[kq][m], Ls[kq + 1][m], Ls[kq + 2][m], Ls[kq + 3][m]);
    *(short4*)(dst + (size_t)(m0 + m) * KPo + k0 + kq) = w;
  }
}

// ---------------- compute_r GEMM v3: global_load_lds staging (no VGPR round-trip) ---------
__global__ __launch_bounds__(256) void k_gemm_cr2(
    const short* __restrict__ AT, const short* __restrict__ XT, float* __restrict__ acc)
{
  const int m0 = blockIdx.x * 128;
  const int n0 = blockIdx.y * 128;
  const int k0 = blockIdx.z * 1568;

  __shared__ short As[128 * 32];
  __shared__ short Bs[128 * 32];
  const int tid = threadIdx.x;
  const int lane = tid & 63, wave = tid >> 6;
  const int wr = wave >> 1, wc = wave & 1;

  // staging: LDS byte offset tid*16 == (tid>>2)*64 + (tid&3)*16 (wave-uniform base + lane*16)
  const int r0 = tid >> 2;
  const int slot = tid & 3;
  const short* gA0 = AT + (size_t)(m0 + r0) * KP + slot * 8;
  const short* gA1 = AT + (size_t)(m0 + r0 + 64) * KP + slot * 8;
  const short* gB0 = XT + (size_t)(n0 + r0) * KP + slot * 8;
  const short* gB1 = XT + (size_t)(n0 + r0 + 64) * KP + slot * 8;
  short* lA0 = As + tid * 8;
  short* lA1 = As + 2048 + tid * 8;
  short* lB0 = Bs + tid * 8;
  short* lB1 = Bs + 2048 + tid * 8;

  f32x4 c[4][4];
  #pragma unroll
  for (int i = 0; i < 4; ++i)
    #pragma unroll
    for (int j = 0; j < 4; ++j)
      #pragma unroll
      for (int q = 0; q < 4; ++q) c[i][j][q] = 0.f;

  const int krow = (lane >> 4) * 8;
  const int rsel = lane & 15;

  for (int kk = k0; kk < k0 + 1568; kk += 32){
    __builtin_amdgcn_global_load_lds((gas_void*)(gA0 + kk), (las_void*)lA0, 16, 0, 0);
    __builtin_amdgcn_global_load_lds((gas_void*)(gA1 + kk), (las_void*)lA1, 16, 0, 0);
    __builtin_amdgcn_global_load_lds((gas_void*)(gB0 + kk), (las_void*)lB0, 16, 0, 0);
    __builtin_amdgcn_global_load_lds((gas_void*)(gB1 + kk), (las_void*)lB1, 16, 0, 0);
    __syncthreads();
    bf16x8 af[4], bfr[4];
    #pragma unroll
    for (int i = 0; i < 4; ++i){
      af[i]  = *(const bf16x8*)(As + (wr * 64 + i * 16 + rsel) * 32 + krow);
      bfr[i] = *(const bf16x8*)(Bs + (wc * 64 + i * 16 + rsel) * 32 + krow);
    }
    #pragma unroll
    for (int i = 0; i < 4; ++i)
      #pragma unroll
      for (int j = 0; j < 4; ++j)
        c[i][j] = __builtin_amdgcn_mfma_f32_16x16x32_bf16(af[i], bfr[j], c[i][j], 0, 0, 0);
    __syncthreads();
  }
  const int col = lane & 15;
  const int rw0 = (lane >> 4) * 4;
  #pragma unroll
  for (int j = 0; j < 4; ++j){
    int dg = n0 + wc * 64 + j * 16 + col;
    if (dg >= DD) continue;
    #pragma unroll
    for (int i = 0; i < 4; ++i){
      int mg = m0 + wr * 64 + i * 16 + rw0;
      #pragma unroll
      for (int q = 0; q < 4; ++q)
        if (mg + q < 1000) atomicAdd(acc + (mg + q) * DD + dg, c[i][j][q]);
    }
  }
}

// ---------------- assemble dual_X from acc ----------------
__global__ void k_assemble(const float* __restrict__ acc, const float* __restrict__ hs,
                           const float* __restrict__ ts, float* __restrict__ dualX){
  int i = blockIdx.x * 256 + threadIdx.x;
  if (i < RR * DD){
    int r = i / DD, d = i - r * DD;
    dualX[r * HH + d]      = acc[r * DD + d]          / (hs[r] + 1e-9f);
    dualX[r * HH + DD + d] = acc[(RR + r) * DD + d]   / (ts[r] + 1e-9f);
  }
}

// ---------------- h = feat @ W.T + bias  (f32, [500,600]x[600,600]^T) ----------------
__global__ __launch_bounds__(256) void k_hgemm(const float* __restrict__ feat, const float* __restrict__ W,
                                               const float* __restrict__ bias, float* __restrict__ h){
  __shared__ float Fs[16][17], Ws[16][17];
  int tx = threadIdx.x & 15, ty = threadIdx.x >> 4;
  int r0 = blockIdx.x * 16, j0 = blockIdx.y * 16;
  float acc = 0.f;
  for (int k0 = 0; k0 < HH; k0 += 16){
    int k = k0 + tx;
    Fs[ty][tx] = (r0 + ty < RR && k < HH) ? feat[(r0 + ty) * HH + k] : 0.f;
    Ws[ty][tx] = (j0 + ty < HH && k < HH) ? W[(j0 + ty) * HH + k] : 0.f;
    __syncthreads();
    #pragma unroll
    for (int kk = 0; kk < 16; ++kk) acc += Fs[ty][kk] * Ws[tx][kk];
    __syncthreads();
  }
  int rr = r0 + ty, jj = j0 + tx;
  if (rr < RR && jj < HH) h[rr * HH + jj] = acc + (bias ? bias[jj] : 0.f);
}

// ---------------- per-row dots: f1[r]=h[r]·a1+b1, f2[r]=h[r]·a2+b2 ----------------
__global__ void k_rowdot2(const float* __restrict__ Hm, const float* __restrict__ a1, const float* __restrict__ b1,
                          const float* __restrict__ a2, const float* __restrict__ b2,
                          float* __restrict__ f1, float* __restrict__ f2){
  int wave = threadIdx.x >> 6, lane = threadIdx.x & 63;
  int r = blockIdx.x * 4 + wave;
  if (r >= RR) return;
  float s1 = 0.f, s2 = 0.f;
  for (int k = lane; k < HH; k += 64){
    float hv = Hm[r * HH + k];
    s1 += hv * a1[k];
    if (a2) s2 += hv * a2[k];
  }
  #pragma unroll
  for (int off = 32; off; off >>= 1){
    s1 += __shfl_down(s1, off);
    s2 += __shfl_down(s2, off);
  }
  if (lane == 0){
    f1[r] = s1 + b1[0];
    if (f2) f2[r] = s2 + (b2 ? b2[0] : 0.f);
  }
}

// ---------------- fused dense attention, 8 rows/block, val-load amortized ----------------
__global__ __launch_bounds__(320) void k_attrow2(const float* __restrict__ f1, const float* __restrict__ f2,
    const float* __restrict__ adj, const float* __restrict__ val, float* __restrict__ outp){
  __shared__ float coef[8][504];
  const int r0 = blockIdx.x * 8;
  const int t = threadIdx.x;
  const int wave = t >> 6, lane = t & 63;

  if (wave < 4){
    #pragma unroll
    for (int sub = 0; sub < 2; ++sub){
      const int slot = wave * 2 + sub;
      const int r = r0 + slot;
      if (r < RR){
        const float f1r = f1[r];
        float lg[8];
        float mx = -3.0e38f;
        #pragma unroll
        for (int cI = 0; cI < 8; ++cI){
          int j = lane + 64 * cI;
          float l = -3.0e38f;
          if (j < RR){
            l = f1r + f2[j];
            l = (l > 0.f) ? l : 0.01f * l;
            if (adj[r * RR + j] <= 0.f) l -= 1e9f;
          }
          lg[cI] = l;
          mx = fmaxf(mx, l);
        }
        #pragma unroll
        for (int off = 32; off; off >>= 1) mx = fmaxf(mx, __shfl_xor(mx, off));
        float sum = 0.f;
        float ev[8];
        #pragma unroll
        for (int cI = 0; cI < 8; ++cI){
          int j = lane + 64 * cI;
          float e = (j < RR) ? expf(lg[cI] - mx) : 0.f;
          ev[cI] = e;
          sum += e;
        }
        #pragma unroll
        for (int off = 32; off; off >>= 1) sum += __shfl_xor(sum, off);
        float inv = 1.f / sum;
        #pragma unroll
        for (int cI = 0; cI < 8; ++cI){
          int j = lane + 64 * cI;
          if (j < RR) coef[slot][j] = ev[cI] * inv;
        }
      } else {
        #pragma unroll
        for (int cI = 0; cI < 8; ++cI){
          int j = lane + 64 * cI;
          if (j < RR) coef[slot][j] = 0.f;
        }
      }
    }
  }
  __syncthreads();

  if (t < 300){
    const int col = blockIdx.y * 300 + t;
    float acc[8];
    #pragma unroll
    for (int rI = 0; rI < 8; ++rI) acc[rI] = 0.f;
    for (int j = 0; j < RR; j += 4){
      float v0 = val[(j + 0) * HH + col];
      float v1 = val[(j + 1) * HH + col];
      float v2 = val[(j + 2) * HH + col];
      float v3 = val[(j + 3) * HH + col];
      #pragma unroll
      for (int rI = 0; rI < 8; ++rI){
        f32x4 cf = *(const f32x4*)&coef[rI][j];
        acc[rI] += cf[0] * v0 + cf[1] * v1 + cf[2] * v2 + cf[3] * v3;
      }
    }
    #pragma unroll
    for (int rI = 0; rI < 8; ++rI){
      int r = r0 + rI;
      if (r < RR) outp[r * HH + col] = fmaxf(acc[rI], 0.f);
    }
  }
}

// ---------------- global-softmax coefficients per relation ----------------
__global__ void k_cvec(const float* __restrict__ tv, const int* __restrict__ cnt, float* __restrict__ cvec){
  __shared__ float red[512];
  int t = threadIdx.x;
  float lr = -3.0e38f, tval = 0.f;
  if (t < RR){
    tval = tv[t];
    tval = (tval > 0.f) ? tval : 0.01f * tval;
    if (cnt[t] > 0) lr = tval;
  }
  red[t] = lr; __syncthreads();
  for (int off = 256; off; off >>= 1){ if (t < off) red[t] = fmaxf(red[t], red[t + off]); __syncthreads(); }
  float mx = red[0]; __syncthreads();
  float ex = (t < RR) ? expf(tval - mx) : 0.f;
  red[t] = (t < RR) ? ex * (float)cnt[t] : 0.f; __syncthreads();
  for (int off = 256; off; off >>= 1){ if (t < off) red[t] += red[t + off]; __syncthreads(); }
  float inv = 1.f / red[0];
  if (t < RR) cvec[t] = ex * inv;
}

// ---------------- sparse att SpMM: out = base + scale*relu(sum c[rv]*X[src]) ----------------
__global__ __launch_bounds__(256) void k_spmm_r(const int* __restrict__ rowst, const int* __restrict__ rowcnt,
    const int* __restrict__ colv, const int* __restrict__ rvv, const float* __restrict__ cvec,
    const float* __restrict__ Xg, const float* __restrict__ base, float scale, float* __restrict__ outp){
  int wave = threadIdx.x >> 6, lane = threadIdx.x & 63;
  int row = blockIdx.x * 4 + wave;
  if (row >= NN) return;
  int st = rowst[row], cn = rowcnt[row];
  float a0 = 0.f, a1 = 0.f, a2 = 0.f, a3 = 0.f, a4 = 0.f;
  for (int e = 0; e < cn; ++e){
    int s = colv[st + e];
    float w = cvec[rvv[st + e]];
    const float* xr = Xg + (size_t)s * DD;
    a0 += w * xr[lane];
    a1 += w * xr[lane + 64];
    a2 += w * xr[lane + 128];
    a3 += w * xr[lane + 192];
    if (lane < 44) a4 += w * xr[lane + 256];
  }
  size_t ro = (size_t)row * DD;
  outp[ro + lane]       = base[ro + lane]       + scale * fmaxf(a0, 0.f);
  outp[ro + lane + 64]  = base[ro + lane + 64]  + scale * fmaxf(a1, 0.f);
  outp[ro + lane + 128] = base[ro + lane + 128] + scale * fmaxf(a2, 0.f);
  outp[ro + lane + 192] = base[ro + lane + 192] + scale * fmaxf(a3, 0.f);
  if (lane < 44) outp[ro + lane + 256] = base[ro + lane + 256] + scale * fmaxf(a4, 0.f);
}

// ---------------- diag-GCN SpMM + highway blend ----------------
__global__ __launch_bounds__(256) void k_spmm_m(const int* __restrict__ rowst, const int* __restrict__ rowcnt,
    const int* __restrict__ colv, const float* __restrict__ mvv,
    const float* __restrict__ Xg, const float* __restrict__ w0, const float* __restrict__ tg,
    const float* __restrict__ base, float* __restrict__ outp){
  int wave = threadIdx.x >> 6, lane = threadIdx.x & 63;
  int row = blockIdx.x * 4 + wave;
  if (row >= NN) return;
  int st = rowst[row], cn = rowcnt[row];
  float a0 = 0.f, a1 = 0.f, a2 = 0.f, a3 = 0.f, a4 = 0.f;
  for (int e = 0; e < cn; ++e){
    int s = colv[st + e];
    float w = mvv[st + e];
    const float* xr = Xg + (size_t)s * DD;
    a0 += w * xr[lane];
    a1 += w * xr[lane + 64];
    a2 += w * xr[lane + 128];
    a3 += w * xr[lane + 192];
    if (lane < 44) a4 += w * xr[lane + 256];
  }
  size_t ro = (size_t)row * DD;
  #pragma unroll
  for (int u = 0; u < 5; ++u){
    int d = lane + u * 64;
    if (d < DD){
      float acc = (u == 0) ? a0 : (u == 1) ? a1 : (u == 2) ? a2 : (u == 3) ? a3 : a4;
      float g = fmaxf(w0[d] * acc, 0.f);
      float tvv = tg[ro + d];
      outp[ro + d] = tvv * g + (1.f - tvv) * base[ro + d];
    }
  }
}

// ---------------- highway gate GEMM v2: Tg = sigmoid(Xin @ Wg + bg) with WgT bf16 ----------
__global__ __launch_bounds__(256) void k_gate2(const float* __restrict__ Xin,
                                               const short* __restrict__ WgT,
                                               const float* __restrict__ bg, float* __restrict__ Tg){
  const int m0 = blockIdx.x * 128, n0 = blockIdx.y * 128;
  __shared__ short As[128 * 32];
  __shared__ short Bs[128 * 32];
  const int tid = threadIdx.x;
  const int lane = tid & 63, wave = tid >> 6;
  const int wr = wave >> 1, wc = wave & 1;

  const int r0 = tid >> 2;
  const int slot = tid & 3;
  const size_t bgA = (size_t)(n0 + r0) * KPW + slot * 8;
  const size_t bgB = (size_t)(n0 + r0 + 64) * KPW + slot * 8;
  short* blA = Bs + r0 * 32 + slot * 8;
  short* blB = Bs + (r0 + 64) * 32 + slot * 8;

  f32x4 c[4][4];
  #pragma unroll
  for (int i = 0; i < 4; ++i)
    #pragma unroll
    for (int j = 0; j < 4; ++j)
      #pragma unroll
      for (int q = 0; q < 4; ++q) c[i][j][q] = 0.f;

  const int krow = (lane >> 4) * 8;
  const int rsel = lane & 15;

  for (int kk = 0; kk < KPW; kk += 32){
    #pragma unroll
    for (int u = 0; u < 4; ++u){
      int f4 = tid + u * 256;
      int ml = f4 >> 3;
      int kl = (f4 & 7) * 4;
      int mg = m0 + ml, kg = kk + kl;
      float4 v = {0.f, 0.f, 0.f, 0.f};
      if (mg < NN && kg < DD) v = *(const float4*)(Xin + (size_t)mg * DD + kg);
      ushort4 w = make_ushort4((unsigned short)f2bf(v.x), (unsigned short)f2bf(v.y),
                               (unsigned short)f2bf(v.z), (unsigned short)f2bf(v.w));
      *reinterpret_cast<ushort4*>(&As[ml * 32 + kl]) = w;
    }
    *(bf16x8*)blA = *(const bf16x8*)(WgT + bgA + kk);
    *(bf16x8*)blB = *(const bf16x8*)(WgT + bgB + kk);
    __syncthreads();
    bf16x8 af[4], bfr[4];
    #pragma unroll
    for (int i = 0; i < 4; ++i){
      af[i]  = *(const bf16x8*)(As + (wr * 64 + i * 16 + rsel) * 32 + krow);
      bfr[i] = *(const bf16x8*)(Bs + (wc * 64 + i * 16 + rsel) * 32 + krow);
    }
    #pragma unroll
    for (int i = 0; i < 4; ++i)
      #pragma unroll
      for (int j = 0; j < 4; ++j)
        c[i][j] = __builtin_amdgcn_mfma_f32_16x16x32_bf16(af[i], bfr[j], c[i][j], 0, 0, 0);
    __syncthreads();
  }
  const int col = lane & 15;
  const int rw0 = (lane >> 4) * 4;
  #pragma unroll
  for (int j = 0; j < 4; ++j){
    int ng = n0 + wc * 64 + j * 16 + col;
    if (ng >= DD) continue;
    float bias = bg[ng];
    #pragma unroll
    for (int i = 0; i < 4; ++i){
      int mg = m0 + wr * 64 + i * 16 + rw0;
      #pragma unroll
      for (int q = 0; q < 4; ++q){
        if (mg + q < NN){
          float x = c[i][j][q] + bias;
          Tg[(size_t)(mg + q) * DD + ng] = 1.f / (1.f + expf(-x));
        }
      }
    }
  }
}

// ================= host =================
extern "C" void kernel_launch(void* const* d_in, const int* in_sizes, int n_in,
                              void* d_out, int out_size, void* d_ws, size_t ws_size,
                              hipStream_t stream)
{
  (void)in_sizes; (void)n_in; (void)out_size; (void)ws_size;
  const float* X0   = (const float*)d_in[0];
  const float* head = (const float*)d_in[1];
  const float* tail = (const float*)d_in[2];
  const float* adj  = (const float*)d_in[3];
  const int*   ridx = (const int*)d_in[4];
  const int*   rval = (const int*)d_in[5];
  const int*   midx = (const int*)d_in[6];
  const float* mval = (const float*)d_in[7];
  const float* W_s  = (const float*)d_in[8];
  const float* a1_s = (const float*)d_in[9];
  const float* b1_s = (const float*)d_in[10];
  const float* a2_s = (const float*)d_in[11];
  const float* b2_s = (const float*)d_in[12];
  const float* w_sp1= (const float*)d_in[13];
  const float* b_sp1= (const float*)d_in[14];
  const float* w_sp2= (const float*)d_in[15];
  const float* b_sp2= (const float*)d_in[16];
  const float* W_d  = (const float*)d_in[17];
  const float* b_d  = (const float*)d_in[18];
  const float* a1_d = (const float*)d_in[19];
  const float* b1_d = (const float*)d_in[20];
  const float* a2_d = (const float*)d_in[21];
  const float* b2_d = (const float*)d_in[22];
  const float* w0_1 = (const float*)d_in[23];
  const float* w0_2 = (const float*)d_in[24];
  const float* Wg1  = (const float*)d_in[25];
  const float* bg1  = (const float*)d_in[26];
  const float* Wg2  = (const float*)d_in[27];
  const float* bg2  = (const float*)d_in[28];

  char* ws = (char*)d_ws;
  size_t off = 0;
  auto alloc = [&](size_t bytes)->char*{
    char* p = ws + off;
    off += (bytes + 255) & ~(size_t)255;
    return p;
  };
  float* acc    = (float*)alloc(1000 * DD * 4);
  float* X1GC   = (float*)alloc((size_t)NN * DD * 4);
  float* X2     = (float*)alloc((size_t)NN * DD * 4);
  float* TG     = (float*)alloc((size_t)NN * DD * 4);   // aliased with XT (lifetimes disjoint)
  float* dualX  = (float*)alloc(RR * HH * 4);
  float* dualH1 = (float*)alloc(RR * HH * 4);
  float* dualH2 = (float*)alloc(RR * HH * 4);
  float* hbuf   = (float*)alloc(RR * HH * 4);
  float* hs     = (float*)alloc(2048);
  float* ts     = (float*)alloc(2048);
  int*   cntR   = (int*)alloc(2048);
  float* f1     = (float*)alloc(2048);
  float* f2     = (float*)alloc(2048);
  float* tv     = (float*)alloc(2048);
  float* cv     = (float*)alloc(2048);
  int* rowcntR  = (int*)alloc((size_t)NN * 4);
  int* rowstR   = (int*)alloc((size_t)NN * 4);
  int* curR     = (int*)alloc((size_t)NN * 4);
  int* colR     = (int*)alloc((size_t)EE * 4);
  int* rvR      = (int*)alloc((size_t)EE * 4);
  int* rowcntM  = (int*)alloc((size_t)NN * 4);
  int* rowstM   = (int*)alloc((size_t)NN * 4);
  int* curM     = (int*)alloc((size_t)NN * 4);
  int* colM     = (int*)alloc((size_t)EE * 4);
  float* mvM    = (float*)alloc((size_t)EE * 4);
  int* incl     = (int*)alloc((size_t)NN * 4);
  int* bsum     = (int*)alloc(1024);
  int* boff     = (int*)alloc(1024);
  short* WgT1   = (short*)alloc((size_t)384 * KPW * 2);
  short* WgT2   = (short*)alloc((size_t)384 * KPW * 2);
  short* AT     = (short*)alloc((size_t)1024 * KP * 2);   // 102.8 MB, built once

  short* XT = (short*)TG;   // 384*KP*2 = 38.5 MB fits in TG's 60 MB region

  float* OUT0 = (float*)d_out;
  float* OUT1 = (float*)d_out + (size_t)NN * DD;

  hipMemsetAsync(hs, 0, 3 * 2048, stream);
  hipMemsetAsync(rowcntR, 0, (size_t)NN * 4, stream);
  hipMemsetAsync(rowcntM, 0, (size_t)NN * 4, stream);

  // ---- static prep ----
  k_hist_lds<<<256, 256, RR * 4, stream>>>(rval, EE, RR, cntR);
  k_hist_glob<<<512, 256, 0, stream>>>(ridx, EE, rowcntR);
  k_scan_part<<<196, 256, 0, stream>>>(rowcntR, NN, incl, bsum);
  k_scan_mid<<<1, 1, 0, stream>>>(bsum, 196, boff);
  k_scan_add<<<196, 256, 0, stream>>>(incl, rowcntR, boff, NN, rowstR, curR);
  k_scatter_r<<<512, 256, 0, stream>>>(ridx, ridx + EE, rval, EE, curR, colR, rvR);
  k_hist_glob<<<512, 256, 0, stream>>>(midx, EE, rowcntM);
  k_scan_part<<<196, 256, 0, stream>>>(rowcntM, NN, incl, bsum);
  k_scan_mid<<<1, 1, 0, stream>>>(bsum, 196, boff);
  k_scan_add<<<196, 256, 0, stream>>>(incl, rowcntM, boff, NN, rowstM, curM);
  k_scatter_m<<<512, 256, 0, stream>>>(midx, midx + EE, mval, EE, curM, colM, mvM);
  k_prep_at<<<dim3(784, 16), 256, 0, stream>>>(head, tail, AT, hs, ts);
  k_prep_t<<<dim3(5, 6), 256, 0, stream>>>(Wg1, DD, DD, WgT1, KPW);
  k_prep_t<<<dim3(5, 6), 256, 0, stream>>>(Wg2, DD, DD, WgT2, KPW);

  // ---- round 1 ----
  hipMemsetAsync(acc, 0, 1000 * DD * 4, stream);
  k_prep_t<<<dim3(784, 6), 256, 0, stream>>>(X0, NN, DD, XT, KP);
  k_gemm_cr2<<<dim3(8, 3, 32), 256, 0, stream>>>(AT, XT, acc);
  k_assemble<<<586, 256, 0, stream>>>(acc, hs, ts, dualX);
  k_hgemm<<<dim3(32, 38), 256, 0, stream>>>(dualX, W_s, nullptr, hbuf);
  k_rowdot2<<<125, 256, 0, stream>>>(hbuf, a1_s, b1_s, a2_s, b2_s, f1, f2);
  k_attrow2<<<dim3(63, 2), 320, 0, stream>>>(f1, f2, adj, dualX, dualH1);
  k_rowdot2<<<125, 256, 0, stream>>>(dualH1, w_sp1, b_sp1, nullptr, nullptr, tv, nullptr);
  k_cvec<<<1, 512, 0, stream>>>(tv, cntR, cv);
  k_spmm_r<<<12500, 256, 0, stream>>>(rowstR, rowcntR, colR, rvR, cv, X0, X0, 0.1f, X1GC);

  // ---- round 2 ----
  hipMemsetAsync(acc, 0, 1000 * DD * 4, stream);
  k_prep_t<<<dim3(784, 6), 256, 0, stream>>>(X1GC, NN, DD, XT, KP);
  k_gemm_cr2<<<dim3(8, 3, 32), 256, 0, stream>>>(AT, XT, acc);
  k_assemble<<<586, 256, 0, stream>>>(acc, hs, ts, dualX);
  k_hgemm<<<dim3(32, 38), 256, 0, stream>>>(dualX, W_d, b_d, hbuf);
  k_rowdot2<<<125, 256, 0, stream>>>(hbuf, a1_d, b1_d, a2_d, b2_d, f1, f2);
  k_attrow2<<<dim3(63, 2), 320, 0, stream>>>(f1, f2, adj, dualH1, dualH2);
  k_rowdot2<<<125, 256, 0, stream>>>(dualH2, w_sp2, b_sp2, nullptr, nullptr, tv, nullptr);
  k_cvec<<<1, 512, 0, stream>>>(tv, cntR, cv);
  k_spmm_r<<<12500, 256, 0, stream>>>(rowstR, rowcntR, colR, rvR, cv, X1GC, X0, 0.3f, X2);

  // ---- GCN + highway ----
  k_gate2<<<dim3(391, 3), 256, 0, stream>>>(X2, WgT1, bg1, TG);
  k_spmm_m<<<12500, 256, 0, stream>>>(rowstM, rowcntM, colM, mvM, X2, w0_1, TG, X2, X1GC);
  k_gate2<<<dim3(391, 3), 256, 0, stream>>>(X1GC, WgT2, bg2, TG);
  k_spmm_m<<<12500, 256, 0, stream>>>(rowstM, rowcntM, colM, mvM, X1GC, w0_2, TG, X1GC, OUT0);

  // ---- round 3 (dual only) ----
  hipMemsetAsync(acc, 0, 1000 * DD * 4, stream);
  k_prep_t<<<dim3(784, 6), 256, 0, stream>>>(OUT0, NN, DD, XT, KP);
  k_gemm_cr2<<<dim3(8, 3, 32), 256, 0, stream>>>(AT, XT, acc);
  k_assemble<<<586, 256, 0, stream>>>(acc, hs, ts, dualX);
  k_hgemm<<<dim3(32, 38), 256, 0, stream>>>(dualX, W_d, b_d, hbuf);
  k_rowdot2<<<125, 256, 0, stream>>>(hbuf, a1_d, b1_d, a2_d, b2_d, f1, f2);
  k_attrow2<<<dim3(63, 2), 320, 0, stream>>>(f1, f2, adj, dualH2, OUT1);
}